// Round 9
// baseline (403.439 us; speedup 1.0000x reference)
//
#include <hip/hip_runtime.h>

typedef unsigned short u16;
typedef __attribute__((ext_vector_type(8))) short bf16x8;   // 8 bf16 in 4 VGPRs
typedef __attribute__((ext_vector_type(4))) float f32x4;

#define MFMA16(a, b, c) __builtin_amdgcn_mfma_f32_16x16x32_bf16(a, b, c, 0, 0, 0)

__device__ __forceinline__ float b2f(u16 u) {
    unsigned int x = ((unsigned int)u) << 16;
    return __builtin_bit_cast(float, x);
}
__device__ __forceinline__ u16 f2b(float f) {
    unsigned int u = __builtin_bit_cast(unsigned int, f);
    u = u + 0x7fffu + ((u >> 16) & 1u);   // round-to-nearest-even
    return (u16)(u >> 16);
}
// tanh-form GELU: x*t/(1+t), t=exp2(x*(2.3022+0.10295 x^2)); clamped arg -> no inf/NaN.
// max |err| vs exact erf-GELU ~3e-3, negligible vs bf16 tolerance.
__device__ __forceinline__ float gelu_t(float x) {
    float xc = fminf(fmaxf(x, -8.f), 8.f);
    float tt = __builtin_amdgcn_exp2f(xc * (2.3022077f + 0.1029483f * xc * xc));
    return x * tt * __builtin_amdgcn_rcpf(1.f + tt);
}
__device__ __forceinline__ float gelu_f(float x) {
    return 0.5f * x * (1.0f + erff(x * 0.70710678118654752f));  // exact (QKV path unused)
}
__device__ __forceinline__ void gload_lds16(const u16* g, u16* lds) {
    __builtin_amdgcn_global_load_lds(
        (const __attribute__((address_space(1))) unsigned int*)g,
        (__attribute__((address_space(3))) unsigned int*)lds, 16, 0, 0);
}
__device__ __forceinline__ void barrier_raw() {
    asm volatile("" ::: "memory");
    __builtin_amdgcn_s_barrier();
    asm volatile("" ::: "memory");
}
// T1: bijective XCD-aware block remap (m204).
__device__ __forceinline__ void swz_block(int& mb, int& nb) {
    const int NX = gridDim.x;
    const int nwg = NX * gridDim.y;
    const int wg = blockIdx.y * NX + blockIdx.x;
    const int q = nwg >> 3, rmd = nwg & 7;
    const int xcd = wg & 7, idx = wg >> 3;
    const int swz = (xcd < rmd ? xcd * (q + 1) : rmd * (q + 1) + (xcd - rmd) * q) + idx;
    mb = swz / NX;
    nb = swz - mb * NX;
}

// ---------------------------------------------------------------------------
// fp32 -> bf16 cast
// ---------------------------------------------------------------------------
__global__ __launch_bounds__(256) void cvt_f2b_kernel(
    const float* __restrict__ in, u16* __restrict__ out, int n)
{
    const int i = (blockIdx.x * 256 + threadIdx.x) * 4;
    if (i >= n) return;
    float4 v = *(const float4*)&in[i];
    ushort4 o;
    o.x = f2b(v.x); o.y = f2b(v.y); o.z = f2b(v.z); o.w = f2b(v.w);
    *(ushort4*)&out[i] = o;
}

// ---------------------------------------------------------------------------
// fp32 [R][C] -> bf16 transposed [C][R]
// ---------------------------------------------------------------------------
__global__ __launch_bounds__(256) void transpose_cvt(
    const float* __restrict__ in, u16* __restrict__ out, int R, int C)
{
    __shared__ u16 tile[64][65];
    const int t = threadIdx.x;
    const int r0 = blockIdx.y * 64, c0 = blockIdx.x * 64;
    const int tr = t >> 4, tc = (t & 15) * 4;
#pragma unroll
    for (int p = 0; p < 4; p++) {
        const int rr = tr + p * 16;
        float4 v = *(const float4*)&in[(size_t)(r0 + rr) * C + c0 + tc];
        tile[rr][tc + 0] = f2b(v.x); tile[rr][tc + 1] = f2b(v.y);
        tile[rr][tc + 2] = f2b(v.z); tile[rr][tc + 3] = f2b(v.w);
    }
    __syncthreads();
#pragma unroll
    for (int p = 0; p < 4; p++) {
        const int cc = tr + p * 16;
        ushort4 v;
        v.x = tile[tc + 0][cc]; v.y = tile[tc + 1][cc];
        v.z = tile[tc + 2][cc]; v.w = tile[tc + 3][cc];
        *(ushort4*)&out[(size_t)(c0 + cc) * R + r0 + tc] = v;
    }
}

// ---------------------------------------------------------------------------
// 8-phase GEMM (T2+T3+T4+T5): C[M][N] = A[M][K] @ Bt[N][K]^T + bias.
// BM = TM*32 (TM=8 -> 256x256 tile; TM=4 -> 128x256), BN=256, 8 waves (2Mx4N),
// 512 thr. LDS = ring of 4 K=32 slices (A+B), staged by global_load_lds with
// pre-swizzled source (slot ^= row&3, rule 21); reads use matching XOR.
// Counted vmcnt (never 0 mid-loop): steady leave = 2 slices' stages in flight.
// EPI: 0 = plain, 1 = tanh-GELU.
// ---------------------------------------------------------------------------
template <int TM, int EPI>
__global__ __launch_bounds__(512, 2) void gemm8p(
    const u16* __restrict__ A, const u16* __restrict__ Bt,
    const float* __restrict__ bias, u16* __restrict__ C,
    int M, int N, int K)
{
    constexpr int BM = TM * 32;          // 256 or 128
    constexpr int LA = BM / 128;         // staging instrs per A-slice (2 or 1)
    __shared__ __attribute__((aligned(16))) u16 As[4][BM][32];
    __shared__ __attribute__((aligned(16))) u16 Bs[4][256][32];

    const int t = threadIdx.x;
    const int lane = t & 63;
    const int g = lane >> 4, r = lane & 15;
    const int wid = t >> 6, wm = wid >> 2, wn = wid & 3;
    int mb, nb;
    swz_block(mb, nb);                   // gridDim.x = N-tiles
    const int m0 = mb * BM, n0 = nb * 256;

    const int srow = t >> 2;                       // staging row (0..127)
    const int sslot = ((t & 3) ^ (srow & 3)) * 8;  // pre-swizzled source slot

    auto stageA = [&](int u) {
        const int slot = u & 3, ks = u << 5;
#pragma unroll
        for (int h = 0; h < LA; ++h)
            gload_lds16(&A[(size_t)(m0 + srow + h * 128) * K + ks + sslot],
                        &As[slot][srow + h * 128][(t & 3) * 8]);
    };
    auto stageB = [&](int u) {
        const int slot = u & 3, ks = u << 5;
#pragma unroll
        for (int h = 0; h < 2; ++h)
            gload_lds16(&Bt[(size_t)(n0 + srow + h * 128) * K + ks + sslot],
                        &Bs[slot][srow + h * 128][(t & 3) * 8]);
    };

    f32x4 acc[TM][4];
    const f32x4 fz = {0.f, 0.f, 0.f, 0.f};
#pragma unroll
    for (int i = 0; i < TM; ++i)
#pragma unroll
        for (int j = 0; j < 4; ++j) acc[i][j] = fz;

    const int S = K >> 5;   // K=32 slices
    // prologue: 3 slices in flight
    stageA(0); stageB(0); stageA(1); stageB(1); stageA(2); stageB(2);

    const int swA = g ^ (r & 3);   // read-side swizzled slot (row&3 == r&3 for 16-aligned frags)

    for (int s = 0; s < S; ++s) {
        // ---- phase A: wait(slice s landed), stage s+3 A-part, frags+MFMA j0/j1
        if constexpr (TM == 8) {
            if (s < S - 2)       asm volatile("s_waitcnt vmcnt(8)" ::: "memory");
            else if (s == S - 2) asm volatile("s_waitcnt vmcnt(4)" ::: "memory");
            else                 asm volatile("s_waitcnt vmcnt(0)" ::: "memory");
        } else {
            if (s < S - 2)       asm volatile("s_waitcnt vmcnt(6)" ::: "memory");
            else if (s == S - 2) asm volatile("s_waitcnt vmcnt(3)" ::: "memory");
            else                 asm volatile("s_waitcnt vmcnt(0)" ::: "memory");
        }
        if (s + 3 < S) stageA(s + 3);
        barrier_raw();

        const int slot = s & 3;
        bf16x8 af[TM], bf[4];
#pragma unroll
        for (int i = 0; i < TM; ++i)
            af[i] = *(const bf16x8*)&As[slot][wm * (TM * 16) + i * 16 + r][swA * 8];
#pragma unroll
        for (int j = 0; j < 4; ++j)
            bf[j] = *(const bf16x8*)&Bs[slot][wn * 64 + j * 16 + r][swA * 8];

        __builtin_amdgcn_s_setprio(1);
#pragma unroll
        for (int i = 0; i < TM; ++i) {
            acc[i][0] = MFMA16(af[i], bf[0], acc[i][0]);
            acc[i][1] = MFMA16(af[i], bf[1], acc[i][1]);
        }
        __builtin_amdgcn_s_setprio(0);
        barrier_raw();

        // ---- phase B: stage s+3 B-part, MFMA j2/j3
        if (s + 3 < S) stageB(s + 3);
        barrier_raw();
        __builtin_amdgcn_s_setprio(1);
#pragma unroll
        for (int i = 0; i < TM; ++i) {
            acc[i][2] = MFMA16(af[i], bf[2], acc[i][2]);
            acc[i][3] = MFMA16(af[i], bf[3], acc[i][3]);
        }
        __builtin_amdgcn_s_setprio(0);
        barrier_raw();
    }

    // epilogue: C layout col=lane&15, row=(lane>>4)*4+reg
#pragma unroll
    for (int i = 0; i < TM; ++i) {
        const int row0 = m0 + wm * (TM * 16) + i * 16 + g * 4;
#pragma unroll
        for (int j = 0; j < 4; ++j) {
            const int col = n0 + wn * 64 + j * 16 + r;
            const float bs = bias[col];
#pragma unroll
            for (int rg = 0; rg < 4; ++rg) {
                float v = acc[i][j][rg] + bs;
                if (EPI == 1) v = gelu_t(v);
                C[(size_t)(row0 + rg) * N + col] = f2b(v);
            }
        }
    }
}

// ---------------------------------------------------------------------------
// Fused QKV GEMM (m97 structure): N=3072 = [Q|K|V] vs WqkvT[3072][1024].
// ---------------------------------------------------------------------------
__global__ __launch_bounds__(256, 2) void gemm_qkv(
    const u16* __restrict__ A, const u16* __restrict__ Bt,
    const float* __restrict__ bq, const float* __restrict__ bk,
    const float* __restrict__ bv,
    u16* __restrict__ Qo, u16* __restrict__ Ko, u16* __restrict__ Vt,
    int M, int K)
{
    __shared__ __attribute__((aligned(16))) u16 sA[2][128 * 32];
    __shared__ __attribute__((aligned(16))) u16 sB[2][128 * 32];
    const int t = threadIdx.x;
    const int lane = t & 63, w = t >> 6;
    const int g = lane >> 4, r = lane & 15;
    const int wr = w >> 1, wc = w & 1;
    int mb, nb;
    swz_block(mb, nb);
    const int m0 = mb * 128, n0 = nb * 128;
    const int arow0 = t >> 2;
    const int ake = (t & 3) * 8;
    const int ldsb = w * 512;

    const f32x4 fz = {0.f, 0.f, 0.f, 0.f};
    f32x4 acc[4][4];
#pragma unroll
    for (int i = 0; i < 4; i++)
#pragma unroll
        for (int j = 0; j < 4; j++) acc[i][j] = fz;

#pragma unroll
    for (int it = 0; it < 2; ++it) {
        gload_lds16(&A[(size_t)(m0 + arow0 + it * 64) * K + ake], &sA[0][ldsb + it * 2048]);
        gload_lds16(&Bt[(size_t)(n0 + arow0 + it * 64) * K + ake], &sB[0][ldsb + it * 2048]);
    }
    __syncthreads();

    const int nk = K >> 5;
    for (int kt = 0; kt < nk; ++kt) {
        const int buf = kt & 1;
        if (kt + 1 < nk) {
            const int k0 = (kt + 1) << 5;
#pragma unroll
            for (int it = 0; it < 2; ++it) {
                gload_lds16(&A[(size_t)(m0 + arow0 + it * 64) * K + k0 + ake], &sA[buf ^ 1][ldsb + it * 2048]);
                gload_lds16(&Bt[(size_t)(n0 + arow0 + it * 64) * K + k0 + ake], &sB[buf ^ 1][ldsb + it * 2048]);
            }
        }
        bf16x8 af[4], bfr[4];
#pragma unroll
        for (int i = 0; i < 4; i++)
            af[i] = *(const bf16x8*)&sA[buf][(wr * 64 + i * 16 + r) * 32 + g * 8];
#pragma unroll
        for (int j = 0; j < 4; j++)
            bfr[j] = *(const bf16x8*)&sB[buf][(wc * 64 + j * 16 + r) * 32 + g * 8];
#pragma unroll
        for (int i = 0; i < 4; i++)
#pragma unroll
            for (int j = 0; j < 4; j++)
                acc[i][j] = MFMA16(af[i], bfr[j], acc[i][j]);
        __syncthreads();
    }

    const int sel = n0 >> 10;   // 0=Q, 1=K, 2=V
    const float* bias = (sel == 0) ? bq : (sel == 1) ? bk : bv;
#pragma unroll
    for (int i = 0; i < 4; i++) {
#pragma unroll
        for (int j = 0; j < 4; j++) {
            const int col = n0 + wc * 64 + j * 16 + r;
            const int c1 = col & 1023;
            const float bs = bias[c1];
            const int row0 = m0 + wr * 64 + i * 16 + g * 4;
            if (sel < 2) {
                u16* C = sel ? Ko : Qo;
#pragma unroll
                for (int rg = 0; rg < 4; ++rg)
                    C[(size_t)(row0 + rg) * 1024 + c1] = f2b(acc[i][j][rg] + bs);
            } else {
                const int brow = row0 >> 10;
                const int l = row0 & 1023;
                const int vrow = ((brow << 4) + (c1 >> 6)) * 64 + (c1 & 63);
                ushort4 pk;
                pk.x = f2b(acc[i][j][0] + bs);
                pk.y = f2b(acc[i][j][1] + bs);
                pk.z = f2b(acc[i][j][2] + bs);
                pk.w = f2b(acc[i][j][3] + bs);
                *(ushort4*)&Vt[(size_t)vrow * 1024 + l] = pk;
            }
        }
    }
}

// ---------------------------------------------------------------------------
// Flash attention fwd (unchanged from round 6).
// ---------------------------------------------------------------------------
__global__ __launch_bounds__(256, 2) void attn_fwd(
    const u16* __restrict__ Q, const u16* __restrict__ Kb,
    const u16* __restrict__ Vt, u16* __restrict__ O)
{
    __shared__ __attribute__((aligned(16))) u16 sK[2][64 * 64];
    __shared__ __attribute__((aligned(16))) u16 sV[2][64 * 64];
    __shared__ __attribute__((aligned(16))) u16 sP[4][32 * 72];
    const int t = threadIdx.x;
    const int lane = t & 63, w = t >> 6;
    const int g = lane >> 4, r = lane & 15;
    const int bh = blockIdx.y;
    const int b = bh >> 4, h = bh & 15;
    const int q0 = blockIdx.x * 128;
    const size_t tokbase = (size_t)b << 10;
    const float SC = 0.125f * 1.44269504f;

    bf16x8 qf[2][2];
#pragma unroll
    for (int i = 0; i < 2; i++)
#pragma unroll
        for (int c = 0; c < 2; c++)
            qf[i][c] = *(const bf16x8*)&Q[((tokbase + q0 + w * 32 + i * 16 + r) << 10) + h * 64 + c * 32 + g * 8];

    const f32x4 fz = {0.f, 0.f, 0.f, 0.f};
    f32x4 acc[2][4];
    float lrow[2][4];
#pragma unroll
    for (int i = 0; i < 2; i++) {
#pragma unroll
        for (int j = 0; j < 4; j++) acc[i][j] = fz;
#pragma unroll
        for (int rg = 0; rg < 4; rg++) lrow[i][rg] = 0.f;
    }

    const int srow0 = t >> 3;
    const int skesw = ((t & 7) ^ ((t >> 3) & 7)) * 8;
    const int ldsb = w * 512;
    auto stageKV = [&](int kt, int bufsel) {
#pragma unroll
        for (int it = 0; it < 2; ++it) {
            const int row = srow0 + it * 32;
            gload_lds16(&Kb[((tokbase + kt * 64 + row) << 10) + h * 64 + skesw], &sK[bufsel][ldsb + it * 2048]);
            gload_lds16(&Vt[(((size_t)bh * 64 + row) << 10) + kt * 64 + skesw], &sV[bufsel][ldsb + it * 2048]);
        }
    };

    stageKV(0, 0);
    __syncthreads();

    for (int kt = 0; kt < 16; ++kt) {
        const int buf = kt & 1;
        if (kt < 15) stageKV(kt + 1, buf ^ 1);

        f32x4 s[2][4];
#pragma unroll
        for (int i = 0; i < 2; i++)
#pragma unroll
            for (int j = 0; j < 4; j++) s[i][j] = fz;
#pragma unroll
        for (int c = 0; c < 2; c++) {
            bf16x8 kf[4];
#pragma unroll
            for (int j = 0; j < 4; j++)
                kf[j] = *(const bf16x8*)&sK[buf][(j * 16 + r) * 64 + (((c * 4 + g) ^ (r & 7)) * 8)];
#pragma unroll
            for (int i = 0; i < 2; i++)
#pragma unroll
                for (int j = 0; j < 4; j++)
                    s[i][j] = MFMA16(qf[i][c], kf[j], s[i][j]);
        }

#pragma unroll
        for (int i = 0; i < 2; i++) {
#pragma unroll
            for (int rg = 0; rg < 4; rg++) {
                float p0 = __builtin_amdgcn_exp2f(s[i][0][rg] * SC);
                float p1 = __builtin_amdgcn_exp2f(s[i][1][rg] * SC);
                float p2 = __builtin_amdgcn_exp2f(s[i][2][rg] * SC);
                float p3 = __builtin_amdgcn_exp2f(s[i][3][rg] * SC);
                lrow[i][rg] += (p0 + p1) + (p2 + p3);
                const int prow = (i * 16 + g * 4 + rg) * 72;
                sP[w][prow + 0 * 16 + r] = f2b(p0);
                sP[w][prow + 1 * 16 + r] = f2b(p1);
                sP[w][prow + 2 * 16 + r] = f2b(p2);
                sP[w][prow + 3 * 16 + r] = f2b(p3);
            }
        }

#pragma unroll
        for (int c = 0; c < 2; c++) {
            bf16x8 pa[2], vb[4];
#pragma unroll
            for (int i = 0; i < 2; i++)
                pa[i] = *(const bf16x8*)&sP[w][(i * 16 + r) * 72 + c * 32 + g * 8];
#pragma unroll
            for (int j = 0; j < 4; j++)
                vb[j] = *(const bf16x8*)&sV[buf][(j * 16 + r) * 64 + (((c * 4 + g) ^ (r & 7)) * 8)];
#pragma unroll
            for (int i = 0; i < 2; i++)
#pragma unroll
                for (int j = 0; j < 4; j++)
                    acc[i][j] = MFMA16(pa[i], vb[j], acc[i][j]);
        }
        __syncthreads();
    }

#pragma unroll
    for (int i = 0; i < 2; i++)
#pragma unroll
        for (int rg = 0; rg < 4; rg++) {
            float l = lrow[i][rg];
            l += __shfl_xor(l, 1);
            l += __shfl_xor(l, 2);
            l += __shfl_xor(l, 4);
            l += __shfl_xor(l, 8);
            lrow[i][rg] = 1.0f / l;
        }
#pragma unroll
    for (int i = 0; i < 2; i++)
#pragma unroll
        for (int j = 0; j < 4; j++)
#pragma unroll
            for (int rg = 0; rg < 4; rg++) {
                const size_t row = tokbase + q0 + w * 32 + i * 16 + g * 4 + rg;
                const int col = h * 64 + j * 16 + r;
                O[(row << 10) + col] = f2b(acc[i][j][rg] * lrow[i][rg]);
            }
}

// ---------------------------------------------------------------------------
// out = LayerNorm(a + b)
// ---------------------------------------------------------------------------
template <int FP32OUT>
__global__ __launch_bounds__(256) void resln(
    const u16* __restrict__ a, const u16* __restrict__ bsrc, void* __restrict__ optr)
{
    const int row = blockIdx.x, t = threadIdx.x;
    const size_t base = (size_t)row << 10;
    ushort4 va = *(const ushort4*)&a[base + t * 4];
    ushort4 vb = *(const ushort4*)&bsrc[base + t * 4];
    float v0 = b2f(va.x) + b2f(vb.x);
    float v1 = b2f(va.y) + b2f(vb.y);
    float v2 = b2f(va.z) + b2f(vb.z);
    float v3 = b2f(va.w) + b2f(vb.w);
    float s = v0 + v1 + v2 + v3;
    float ss = v0 * v0 + v1 * v1 + v2 * v2 + v3 * v3;
#pragma unroll
    for (int m = 1; m < 64; m <<= 1) { s += __shfl_xor(s, m); ss += __shfl_xor(ss, m); }
    __shared__ float rs[4], rq[4];
    const int w = t >> 6;
    if ((t & 63) == 0) { rs[w] = s; rq[w] = ss; }
    __syncthreads();
    s = rs[0] + rs[1] + rs[2] + rs[3];
    ss = rq[0] + rq[1] + rq[2] + rq[3];
    const float mu = s * (1.0f / 1024.0f);
    const float var = ss * (1.0f / 1024.0f) - mu * mu;
    const float ri = rsqrtf(var + 1e-5f);
    if (FP32OUT) {
        float4 vo;
        vo.x = (v0 - mu) * ri; vo.y = (v1 - mu) * ri;
        vo.z = (v2 - mu) * ri; vo.w = (v3 - mu) * ri;
        *(float4*)&((float*)optr)[base + t * 4] = vo;
    } else {
        ushort4 vo;
        vo.x = f2b((v0 - mu) * ri); vo.y = f2b((v1 - mu) * ri);
        vo.z = f2b((v2 - mu) * ri); vo.w = f2b((v3 - mu) * ri);
        *(ushort4*)&((u16*)optr)[base + t * 4] = vo;
    }
}

// ---------------------------------------------------------------------------
extern "C" void kernel_launch(void* const* d_in, const int* in_sizes, int n_in,
                              void* d_out, int out_size, void* d_ws, size_t ws_size,
                              hipStream_t stream)
{
    (void)in_sizes; (void)n_in; (void)out_size; (void)ws_size;
    const float* x  = (const float*)d_in[0];
    const float* Wq = (const float*)d_in[1];
    const float* bq = (const float*)d_in[2];
    const float* Wk = (const float*)d_in[3];
    const float* bk = (const float*)d_in[4];
    const float* Wv = (const float*)d_in[5];
    const float* bv = (const float*)d_in[6];
    const float* W1 = (const float*)d_in[7];
    const float* b1 = (const float*)d_in[8];
    const float* W2 = (const float*)d_in[9];
    const float* b2 = (const float*)d_in[10];
    float* out = (float*)d_out;
    char* ws = (char*)d_ws;
    const size_t MB = 1u << 20;
    u16* Qb     = (u16*)(ws + 0 * MB);    // 16 MB } later reused as Hb (64 MB)
    u16* Kbf    = (u16*)(ws + 16 * MB);   // 16 MB }
    u16* Vt     = (u16*)(ws + 32 * MB);   // 16 MB }
    u16* Ob     = (u16*)(ws + 48 * MB);   // 16 MB }
    u16* xb     = (u16*)(ws + 64 * MB);   // 16 MB  later reused as H2
    u16* X1     = (u16*)(ws + 80 * MB);   // 16 MB
    u16* W1T    = (u16*)(ws + 96 * MB);   //  8 MB
    u16* WqkvT  = (u16*)(ws + 104 * MB);  //  6 MB } later reused as W2T (8 MB)
    u16* W2T    = (u16*)(ws + 104 * MB);
    u16* Hb     = (u16*)(ws + 0 * MB);    // [8192][4096] bf16 = 64 MB
    u16* H2     = (u16*)(ws + 64 * MB);

    dim3 blk(256);
    cvt_f2b_kernel<<<dim3(8192), blk, 0, stream>>>(x, xb, 8192 * 1024);
    transpose_cvt<<<dim3(16, 16), blk, 0, stream>>>(Wq, WqkvT, 1024, 1024);
    transpose_cvt<<<dim3(16, 16), blk, 0, stream>>>(Wk, WqkvT + 1024 * 1024, 1024, 1024);
    transpose_cvt<<<dim3(16, 16), blk, 0, stream>>>(Wv, WqkvT + 2048 * 1024, 1024, 1024);
    transpose_cvt<<<dim3(64, 16), blk, 0, stream>>>(W1, W1T, 1024, 4096);

    gemm_qkv<<<dim3(24, 64), blk, 0, stream>>>(xb, WqkvT, bq, bk, bv,
                                               Qb, Kbf, Vt, 8192, 1024);

    transpose_cvt<<<dim3(16, 64), blk, 0, stream>>>(W2, W2T, 4096, 1024);

    attn_fwd<<<dim3(8, 128), blk, 0, stream>>>(Qb, Kbf, Vt, Ob);

    resln<0><<<dim3(8192), blk, 0, stream>>>(xb, Ob, X1);

    // FFN1: 256x256 8-phase, tanh-GELU epilogue. grid = (N/256, M/256)
    gemm8p<8, 1><<<dim3(16, 32), dim3(512), 0, stream>>>(X1, W1T, b1, Hb, 8192, 4096, 1024);
    // FFN2: 128x256 8-phase (fills all 256 CUs). grid = (N/256, M/128)
    gemm8p<4, 0><<<dim3(4, 64), dim3(512), 0, stream>>>(Hb, W2T, b2, H2, 8192, 1024, 4096);

    resln<1><<<dim3(8192), blk, 0, stream>>>(X1, H2, out);
}

// Round 10
// 369.571 us; speedup vs baseline: 1.0916x; 1.0916x over previous
//
#include <hip/hip_runtime.h>

typedef unsigned short u16;
typedef __attribute__((ext_vector_type(8))) short bf16x8;   // 8 bf16 in 4 VGPRs
typedef __attribute__((ext_vector_type(4))) float f32x4;

#define MFMA16(a, b, c) __builtin_amdgcn_mfma_f32_16x16x32_bf16(a, b, c, 0, 0, 0)

__device__ __forceinline__ float b2f(u16 u) {
    unsigned int x = ((unsigned int)u) << 16;
    return __builtin_bit_cast(float, x);
}
__device__ __forceinline__ u16 f2b(float f) {
    unsigned int u = __builtin_bit_cast(unsigned int, f);
    u = u + 0x7fffu + ((u >> 16) & 1u);   // round-to-nearest-even
    return (u16)(u >> 16);
}
__device__ __forceinline__ u16 f2b_hi(float f) {   // truncation: 1 VALU op
    return (u16)(__builtin_bit_cast(unsigned int, f) >> 16);
}
// tanh-form GELU: max |err| vs exact erf-GELU ~3e-3; clamped arg -> no inf/NaN.
__device__ __forceinline__ float gelu_t(float x) {
    float xc = fminf(fmaxf(x, -8.f), 8.f);
    float tt = __builtin_amdgcn_exp2f(xc * (2.3022077f + 0.1029483f * xc * xc));
    return x * tt * __builtin_amdgcn_rcpf(1.f + tt);
}
__device__ __forceinline__ void gload_lds16(const u16* g, u16* lds) {
    __builtin_amdgcn_global_load_lds(
        (const __attribute__((address_space(1))) unsigned int*)g,
        (__attribute__((address_space(3))) unsigned int*)lds, 16, 0, 0);
}
__device__ __forceinline__ void barrier_raw() {
    asm volatile("" ::: "memory");
    __builtin_amdgcn_s_barrier();
    asm volatile("" ::: "memory");
}
// T1: bijective XCD-aware block remap (m204).
__device__ __forceinline__ void swz_block(int& mb, int& nb) {
    const int NX = gridDim.x;
    const int nwg = NX * gridDim.y;
    const int wg = blockIdx.y * NX + blockIdx.x;
    const int q = nwg >> 3, rmd = nwg & 7;
    const int xcd = wg & 7, idx = wg >> 3;
    const int swz = (xcd < rmd ? xcd * (q + 1) : rmd * (q + 1) + (xcd - rmd) * q) + idx;
    mb = swz / NX;
    nb = swz - mb * NX;
}

// ---------------------------------------------------------------------------
// fp32 -> bf16 cast
// ---------------------------------------------------------------------------
__global__ __launch_bounds__(256) void cvt_f2b_kernel(
    const float* __restrict__ in, u16* __restrict__ out, int n)
{
    const int i = (blockIdx.x * 256 + threadIdx.x) * 4;
    if (i >= n) return;
    float4 v = *(const float4*)&in[i];
    ushort4 o;
    o.x = f2b(v.x); o.y = f2b(v.y); o.z = f2b(v.z); o.w = f2b(v.w);
    *(ushort4*)&out[i] = o;
}

// ---------------------------------------------------------------------------
// fp32 [R][C] -> bf16 transposed [C][R]
// ---------------------------------------------------------------------------
__global__ __launch_bounds__(256) void transpose_cvt(
    const float* __restrict__ in, u16* __restrict__ out, int R, int C)
{
    __shared__ u16 tile[64][65];
    const int t = threadIdx.x;
    const int r0 = blockIdx.y * 64, c0 = blockIdx.x * 64;
    const int tr = t >> 4, tc = (t & 15) * 4;
#pragma unroll
    for (int p = 0; p < 4; p++) {
        const int rr = tr + p * 16;
        float4 v = *(const float4*)&in[(size_t)(r0 + rr) * C + c0 + tc];
        tile[rr][tc + 0] = f2b(v.x); tile[rr][tc + 1] = f2b(v.y);
        tile[rr][tc + 2] = f2b(v.z); tile[rr][tc + 3] = f2b(v.w);
    }
    __syncthreads();
#pragma unroll
    for (int p = 0; p < 4; p++) {
        const int cc = tr + p * 16;
        ushort4 v;
        v.x = tile[tc + 0][cc]; v.y = tile[tc + 1][cc];
        v.z = tile[tc + 2][cc]; v.w = tile[tc + 3][cc];
        *(ushort4*)&out[(size_t)(c0 + cc) * R + r0 + tc] = v;
    }
}

// ---------------------------------------------------------------------------
// m97-style GEMM: C[M][N] = A[M][K] @ Bt[N][K]^T + bias. 128x128 tile, BK=32,
// 256 thr (4 waves), 2-phase dbuf, T1 XCD-swizzled grid. EPI: 0 plain, 1 GELU.
// ---------------------------------------------------------------------------
template <int EPI>
__global__ __launch_bounds__(256, 2) void gemm_bt(
    const u16* __restrict__ A, const u16* __restrict__ Bt,
    const float* __restrict__ bias, u16* __restrict__ C,
    int M, int N, int K)
{
    __shared__ __attribute__((aligned(16))) u16 sA[2][128 * 32];
    __shared__ __attribute__((aligned(16))) u16 sB[2][128 * 32];
    const int t = threadIdx.x;
    const int lane = t & 63, w = t >> 6;
    const int g = lane >> 4, r = lane & 15;
    const int wr = w >> 1, wc = w & 1;
    int mb, nb;
    swz_block(mb, nb);
    const int m0 = mb * 128, n0 = nb * 128;
    const int arow0 = t >> 2;
    const int ake = (t & 3) * 8;
    const int ldsb = w * 512;

    const f32x4 fz = {0.f, 0.f, 0.f, 0.f};
    f32x4 acc[4][4];
#pragma unroll
    for (int i = 0; i < 4; i++)
#pragma unroll
        for (int j = 0; j < 4; j++) acc[i][j] = fz;

#pragma unroll
    for (int it = 0; it < 2; ++it) {
        gload_lds16(&A[(size_t)(m0 + arow0 + it * 64) * K + ake], &sA[0][ldsb + it * 2048]);
        gload_lds16(&Bt[(size_t)(n0 + arow0 + it * 64) * K + ake], &sB[0][ldsb + it * 2048]);
    }
    __syncthreads();

    const int nk = K >> 5;
    for (int kt = 0; kt < nk; ++kt) {
        const int buf = kt & 1;
        if (kt + 1 < nk) {
            const int k0 = (kt + 1) << 5;
#pragma unroll
            for (int it = 0; it < 2; ++it) {
                gload_lds16(&A[(size_t)(m0 + arow0 + it * 64) * K + k0 + ake], &sA[buf ^ 1][ldsb + it * 2048]);
                gload_lds16(&Bt[(size_t)(n0 + arow0 + it * 64) * K + k0 + ake], &sB[buf ^ 1][ldsb + it * 2048]);
            }
        }
        bf16x8 af[4], bfr[4];
#pragma unroll
        for (int i = 0; i < 4; i++)
            af[i] = *(const bf16x8*)&sA[buf][(wr * 64 + i * 16 + r) * 32 + g * 8];
#pragma unroll
        for (int j = 0; j < 4; j++)
            bfr[j] = *(const bf16x8*)&sB[buf][(wc * 64 + j * 16 + r) * 32 + g * 8];
#pragma unroll
        for (int i = 0; i < 4; i++)
#pragma unroll
            for (int j = 0; j < 4; j++)
                acc[i][j] = MFMA16(af[i], bfr[j], acc[i][j]);
        __syncthreads();
    }

#pragma unroll
    for (int i = 0; i < 4; i++) {
#pragma unroll
        for (int j = 0; j < 4; j++) {
            const int col = n0 + wc * 64 + j * 16 + r;
            const float bs = bias[col];
            const int row0 = m0 + wr * 64 + i * 16 + g * 4;
#pragma unroll
            for (int rg = 0; rg < 4; ++rg) {
                float v = acc[i][j][rg] + bs;
                if (EPI == 1) v = gelu_t(v);
                C[(size_t)(row0 + rg) * N + col] = f2b(v);
            }
        }
    }
}

// ---------------------------------------------------------------------------
// 8-phase GEMM (T2+T3+T4+T5), 256x256 tile only (TM=8 — the config whose
// read:MFMA (0.375) and barrier:MFMA (0.125) ratios match the verified m201
// template; TM=4 regressed in round 9 and is retired).
// ---------------------------------------------------------------------------
template <int EPI>
__global__ __launch_bounds__(512, 2) void gemm8p(
    const u16* __restrict__ A, const u16* __restrict__ Bt,
    const float* __restrict__ bias, u16* __restrict__ C,
    int M, int N, int K)
{
    __shared__ __attribute__((aligned(16))) u16 As[4][256][32];
    __shared__ __attribute__((aligned(16))) u16 Bs[4][256][32];

    const int t = threadIdx.x;
    const int lane = t & 63;
    const int g = lane >> 4, r = lane & 15;
    const int wid = t >> 6, wm = wid >> 2, wn = wid & 3;
    int mb, nb;
    swz_block(mb, nb);
    const int m0 = mb * 256, n0 = nb * 256;

    const int srow = t >> 2;
    const int sslot = ((t & 3) ^ (srow & 3)) * 8;

    auto stageA = [&](int u) {
        const int slot = u & 3, ks = u << 5;
#pragma unroll
        for (int h = 0; h < 2; ++h)
            gload_lds16(&A[(size_t)(m0 + srow + h * 128) * K + ks + sslot],
                        &As[slot][srow + h * 128][(t & 3) * 8]);
    };
    auto stageB = [&](int u) {
        const int slot = u & 3, ks = u << 5;
#pragma unroll
        for (int h = 0; h < 2; ++h)
            gload_lds16(&Bt[(size_t)(n0 + srow + h * 128) * K + ks + sslot],
                        &Bs[slot][srow + h * 128][(t & 3) * 8]);
    };

    f32x4 acc[8][4];
    const f32x4 fz = {0.f, 0.f, 0.f, 0.f};
#pragma unroll
    for (int i = 0; i < 8; ++i)
#pragma unroll
        for (int j = 0; j < 4; ++j) acc[i][j] = fz;

    const int S = K >> 5;
    stageA(0); stageB(0); stageA(1); stageB(1); stageA(2); stageB(2);

    const int swA = g ^ (r & 3);

    for (int s = 0; s < S; ++s) {
        if (s < S - 2)       asm volatile("s_waitcnt vmcnt(8)" ::: "memory");
        else if (s == S - 2) asm volatile("s_waitcnt vmcnt(4)" ::: "memory");
        else                 asm volatile("s_waitcnt vmcnt(0)" ::: "memory");
        if (s + 3 < S) stageA(s + 3);
        barrier_raw();

        const int slot = s & 3;
        bf16x8 af[8], bf[4];
#pragma unroll
        for (int i = 0; i < 8; ++i)
            af[i] = *(const bf16x8*)&As[slot][wm * 128 + i * 16 + r][swA * 8];
#pragma unroll
        for (int j = 0; j < 4; ++j)
            bf[j] = *(const bf16x8*)&Bs[slot][wn * 64 + j * 16 + r][swA * 8];

        __builtin_amdgcn_s_setprio(1);
#pragma unroll
        for (int i = 0; i < 8; ++i) {
            acc[i][0] = MFMA16(af[i], bf[0], acc[i][0]);
            acc[i][1] = MFMA16(af[i], bf[1], acc[i][1]);
        }
        __builtin_amdgcn_s_setprio(0);
        barrier_raw();

        if (s + 3 < S) stageB(s + 3);
        barrier_raw();
        __builtin_amdgcn_s_setprio(1);
#pragma unroll
        for (int i = 0; i < 8; ++i) {
            acc[i][2] = MFMA16(af[i], bf[2], acc[i][2]);
            acc[i][3] = MFMA16(af[i], bf[3], acc[i][3]);
        }
        __builtin_amdgcn_s_setprio(0);
        barrier_raw();
    }

#pragma unroll
    for (int i = 0; i < 8; ++i) {
        const int row0 = m0 + wm * 128 + i * 16 + g * 4;
#pragma unroll
        for (int j = 0; j < 4; ++j) {
            const int col = n0 + wn * 64 + j * 16 + r;
            const float bs = bias[col];
#pragma unroll
            for (int rg = 0; rg < 4; ++rg) {
                float v = acc[i][j][rg] + bs;
                if (EPI == 1) v = gelu_t(v);
                C[(size_t)(row0 + rg) * N + col] = f2b(v);
            }
        }
    }
}

// ---------------------------------------------------------------------------
// Fused QKV GEMM (m97 structure): N=3072 = [Q|K|V] vs WqkvT[3072][1024].
// ---------------------------------------------------------------------------
__global__ __launch_bounds__(256, 2) void gemm_qkv(
    const u16* __restrict__ A, const u16* __restrict__ Bt,
    const float* __restrict__ bq, const float* __restrict__ bk,
    const float* __restrict__ bv,
    u16* __restrict__ Qo, u16* __restrict__ Ko, u16* __restrict__ Vt,
    int M, int K)
{
    __shared__ __attribute__((aligned(16))) u16 sA[2][128 * 32];
    __shared__ __attribute__((aligned(16))) u16 sB[2][128 * 32];
    const int t = threadIdx.x;
    const int lane = t & 63, w = t >> 6;
    const int g = lane >> 4, r = lane & 15;
    const int wr = w >> 1, wc = w & 1;
    int mb, nb;
    swz_block(mb, nb);
    const int m0 = mb * 128, n0 = nb * 128;
    const int arow0 = t >> 2;
    const int ake = (t & 3) * 8;
    const int ldsb = w * 512;

    const f32x4 fz = {0.f, 0.f, 0.f, 0.f};
    f32x4 acc[4][4];
#pragma unroll
    for (int i = 0; i < 4; i++)
#pragma unroll
        for (int j = 0; j < 4; j++) acc[i][j] = fz;

#pragma unroll
    for (int it = 0; it < 2; ++it) {
        gload_lds16(&A[(size_t)(m0 + arow0 + it * 64) * K + ake], &sA[0][ldsb + it * 2048]);
        gload_lds16(&Bt[(size_t)(n0 + arow0 + it * 64) * K + ake], &sB[0][ldsb + it * 2048]);
    }
    __syncthreads();

    const int nk = K >> 5;
    for (int kt = 0; kt < nk; ++kt) {
        const int buf = kt & 1;
        if (kt + 1 < nk) {
            const int k0 = (kt + 1) << 5;
#pragma unroll
            for (int it = 0; it < 2; ++it) {
                gload_lds16(&A[(size_t)(m0 + arow0 + it * 64) * K + k0 + ake], &sA[buf ^ 1][ldsb + it * 2048]);
                gload_lds16(&Bt[(size_t)(n0 + arow0 + it * 64) * K + k0 + ake], &sB[buf ^ 1][ldsb + it * 2048]);
            }
        }
        bf16x8 af[4], bfr[4];
#pragma unroll
        for (int i = 0; i < 4; i++)
            af[i] = *(const bf16x8*)&sA[buf][(wr * 64 + i * 16 + r) * 32 + g * 8];
#pragma unroll
        for (int j = 0; j < 4; j++)
            bfr[j] = *(const bf16x8*)&sB[buf][(wc * 64 + j * 16 + r) * 32 + g * 8];
#pragma unroll
        for (int i = 0; i < 4; i++)
#pragma unroll
            for (int j = 0; j < 4; j++)
                acc[i][j] = MFMA16(af[i], bfr[j], acc[i][j]);
        __syncthreads();
    }

    const int sel = n0 >> 10;
    const float* bias = (sel == 0) ? bq : (sel == 1) ? bk : bv;
#pragma unroll
    for (int i = 0; i < 4; i++) {
#pragma unroll
        for (int j = 0; j < 4; j++) {
            const int col = n0 + wc * 64 + j * 16 + r;
            const int c1 = col & 1023;
            const float bs = bias[c1];
            const int row0 = m0 + wr * 64 + i * 16 + g * 4;
            if (sel < 2) {
                u16* C = sel ? Ko : Qo;
#pragma unroll
                for (int rg = 0; rg < 4; ++rg)
                    C[(size_t)(row0 + rg) * 1024 + c1] = f2b(acc[i][j][rg] + bs);
            } else {
                const int brow = row0 >> 10;
                const int l = row0 & 1023;
                const int vrow = ((brow << 4) + (c1 >> 6)) * 64 + (c1 & 63);
                ushort4 pk;
                pk.x = f2b(acc[i][j][0] + bs);
                pk.y = f2b(acc[i][j][1] + bs);
                pk.z = f2b(acc[i][j][2] + bs);
                pk.w = f2b(acc[i][j][3] + bs);
                *(ushort4*)&Vt[(size_t)vrow * 1024 + l] = pk;
            }
        }
    }
}

// ---------------------------------------------------------------------------
// Flash attention fwd. sP writes now hi16-truncated (1 VALU op vs 3-4 for RNE;
// bias <= 2^-9 relative on P, absorbed by tolerance).
// ---------------------------------------------------------------------------
__global__ __launch_bounds__(256, 2) void attn_fwd(
    const u16* __restrict__ Q, const u16* __restrict__ Kb,
    const u16* __restrict__ Vt, u16* __restrict__ O)
{
    __shared__ __attribute__((aligned(16))) u16 sK[2][64 * 64];
    __shared__ __attribute__((aligned(16))) u16 sV[2][64 * 64];
    __shared__ __attribute__((aligned(16))) u16 sP[4][32 * 72];
    const int t = threadIdx.x;
    const int lane = t & 63, w = t >> 6;
    const int g = lane >> 4, r = lane & 15;
    const int bh = blockIdx.y;
    const int b = bh >> 4, h = bh & 15;
    const int q0 = blockIdx.x * 128;
    const size_t tokbase = (size_t)b << 10;
    const float SC = 0.125f * 1.44269504f;

    bf16x8 qf[2][2];
#pragma unroll
    for (int i = 0; i < 2; i++)
#pragma unroll
        for (int c = 0; c < 2; c++)
            qf[i][c] = *(const bf16x8*)&Q[((tokbase + q0 + w * 32 + i * 16 + r) << 10) + h * 64 + c * 32 + g * 8];

    const f32x4 fz = {0.f, 0.f, 0.f, 0.f};
    f32x4 acc[2][4];
    float lrow[2][4];
#pragma unroll
    for (int i = 0; i < 2; i++) {
#pragma unroll
        for (int j = 0; j < 4; j++) acc[i][j] = fz;
#pragma unroll
        for (int rg = 0; rg < 4; rg++) lrow[i][rg] = 0.f;
    }

    const int srow0 = t >> 3;
    const int skesw = ((t & 7) ^ ((t >> 3) & 7)) * 8;
    const int ldsb = w * 512;
    auto stageKV = [&](int kt, int bufsel) {
#pragma unroll
        for (int it = 0; it < 2; ++it) {
            const int row = srow0 + it * 32;
            gload_lds16(&Kb[((tokbase + kt * 64 + row) << 10) + h * 64 + skesw], &sK[bufsel][ldsb + it * 2048]);
            gload_lds16(&Vt[(((size_t)bh * 64 + row) << 10) + kt * 64 + skesw], &sV[bufsel][ldsb + it * 2048]);
        }
    };

    stageKV(0, 0);
    __syncthreads();

    for (int kt = 0; kt < 16; ++kt) {
        const int buf = kt & 1;
        if (kt < 15) stageKV(kt + 1, buf ^ 1);

        f32x4 s[2][4];
#pragma unroll
        for (int i = 0; i < 2; i++)
#pragma unroll
            for (int j = 0; j < 4; j++) s[i][j] = fz;
#pragma unroll
        for (int c = 0; c < 2; c++) {
            bf16x8 kf[4];
#pragma unroll
            for (int j = 0; j < 4; j++)
                kf[j] = *(const bf16x8*)&sK[buf][(j * 16 + r) * 64 + (((c * 4 + g) ^ (r & 7)) * 8)];
#pragma unroll
            for (int i = 0; i < 2; i++)
#pragma unroll
                for (int j = 0; j < 4; j++)
                    s[i][j] = MFMA16(qf[i][c], kf[j], s[i][j]);
        }

#pragma unroll
        for (int i = 0; i < 2; i++) {
#pragma unroll
            for (int rg = 0; rg < 4; rg++) {
                float p0 = __builtin_amdgcn_exp2f(s[i][0][rg] * SC);
                float p1 = __builtin_amdgcn_exp2f(s[i][1][rg] * SC);
                float p2 = __builtin_amdgcn_exp2f(s[i][2][rg] * SC);
                float p3 = __builtin_amdgcn_exp2f(s[i][3][rg] * SC);
                lrow[i][rg] += (p0 + p1) + (p2 + p3);
                const int prow = (i * 16 + g * 4 + rg) * 72;
                sP[w][prow + 0 * 16 + r] = f2b_hi(p0);
                sP[w][prow + 1 * 16 + r] = f2b_hi(p1);
                sP[w][prow + 2 * 16 + r] = f2b_hi(p2);
                sP[w][prow + 3 * 16 + r] = f2b_hi(p3);
            }
        }

#pragma unroll
        for (int c = 0; c < 2; c++) {
            bf16x8 pa[2], vb[4];
#pragma unroll
            for (int i = 0; i < 2; i++)
                pa[i] = *(const bf16x8*)&sP[w][(i * 16 + r) * 72 + c * 32 + g * 8];
#pragma unroll
            for (int j = 0; j < 4; j++)
                vb[j] = *(const bf16x8*)&sV[buf][(j * 16 + r) * 64 + (((c * 4 + g) ^ (r & 7)) * 8)];
#pragma unroll
            for (int i = 0; i < 2; i++)
#pragma unroll
                for (int j = 0; j < 4; j++)
                    acc[i][j] = MFMA16(pa[i], vb[j], acc[i][j]);
        }
        __syncthreads();
    }

#pragma unroll
    for (int i = 0; i < 2; i++)
#pragma unroll
        for (int rg = 0; rg < 4; rg++) {
            float l = lrow[i][rg];
            l += __shfl_xor(l, 1);
            l += __shfl_xor(l, 2);
            l += __shfl_xor(l, 4);
            l += __shfl_xor(l, 8);
            lrow[i][rg] = 1.0f / l;
        }
#pragma unroll
    for (int i = 0; i < 2; i++)
#pragma unroll
        for (int j = 0; j < 4; j++)
#pragma unroll
            for (int rg = 0; rg < 4; rg++) {
                const size_t row = tokbase + q0 + w * 32 + i * 16 + g * 4 + rg;
                const int col = h * 64 + j * 16 + r;
                O[(row << 10) + col] = f2b(acc[i][j][rg] * lrow[i][rg]);
            }
}

// ---------------------------------------------------------------------------
// out = LayerNorm(a + b)
// ---------------------------------------------------------------------------
template <int FP32OUT>
__global__ __launch_bounds__(256) void resln(
    const u16* __restrict__ a, const u16* __restrict__ bsrc, void* __restrict__ optr)
{
    const int row = blockIdx.x, t = threadIdx.x;
    const size_t base = (size_t)row << 10;
    ushort4 va = *(const ushort4*)&a[base + t * 4];
    ushort4 vb = *(const ushort4*)&bsrc[base + t * 4];
    float v0 = b2f(va.x) + b2f(vb.x);
    float v1 = b2f(va.y) + b2f(vb.y);
    float v2 = b2f(va.z) + b2f(vb.z);
    float v3 = b2f(va.w) + b2f(vb.w);
    float s = v0 + v1 + v2 + v3;
    float ss = v0 * v0 + v1 * v1 + v2 * v2 + v3 * v3;
#pragma unroll
    for (int m = 1; m < 64; m <<= 1) { s += __shfl_xor(s, m); ss += __shfl_xor(ss, m); }
    __shared__ float rs[4], rq[4];
    const int w = t >> 6;
    if ((t & 63) == 0) { rs[w] = s; rq[w] = ss; }
    __syncthreads();
    s = rs[0] + rs[1] + rs[2] + rs[3];
    ss = rq[0] + rq[1] + rq[2] + rq[3];
    const float mu = s * (1.0f / 1024.0f);
    const float var = ss * (1.0f / 1024.0f) - mu * mu;
    const float ri = rsqrtf(var + 1e-5f);
    if (FP32OUT) {
        float4 vo;
        vo.x = (v0 - mu) * ri; vo.y = (v1 - mu) * ri;
        vo.z = (v2 - mu) * ri; vo.w = (v3 - mu) * ri;
        *(float4*)&((float*)optr)[base + t * 4] = vo;
    } else {
        ushort4 vo;
        vo.x = f2b((v0 - mu) * ri); vo.y = f2b((v1 - mu) * ri);
        vo.z = f2b((v2 - mu) * ri); vo.w = f2b((v3 - mu) * ri);
        *(ushort4*)&((u16*)optr)[base + t * 4] = vo;
    }
}

// ---------------------------------------------------------------------------
extern "C" void kernel_launch(void* const* d_in, const int* in_sizes, int n_in,
                              void* d_out, int out_size, void* d_ws, size_t ws_size,
                              hipStream_t stream)
{
    (void)in_sizes; (void)n_in; (void)out_size; (void)ws_size;
    const float* x  = (const float*)d_in[0];
    const float* Wq = (const float*)d_in[1];
    const float* bq = (const float*)d_in[2];
    const float* Wk = (const float*)d_in[3];
    const float* bk = (const float*)d_in[4];
    const float* Wv = (const float*)d_in[5];
    const float* bv = (const float*)d_in[6];
    const float* W1 = (const float*)d_in[7];
    const float* b1 = (const float*)d_in[8];
    const float* W2 = (const float*)d_in[9];
    const float* b2 = (const float*)d_in[10];
    float* out = (float*)d_out;
    char* ws = (char*)d_ws;
    const size_t MB = 1u << 20;
    u16* Qb     = (u16*)(ws + 0 * MB);    // 16 MB } later reused as Hb (64 MB)
    u16* Kbf    = (u16*)(ws + 16 * MB);   // 16 MB }
    u16* Vt     = (u16*)(ws + 32 * MB);   // 16 MB }
    u16* Ob     = (u16*)(ws + 48 * MB);   // 16 MB }
    u16* xb     = (u16*)(ws + 64 * MB);   // 16 MB  later reused as H2
    u16* X1     = (u16*)(ws + 80 * MB);   // 16 MB
    u16* W1T    = (u16*)(ws + 96 * MB);   //  8 MB
    u16* WqkvT  = (u16*)(ws + 104 * MB);  //  6 MB } later reused as W2T (8 MB)
    u16* W2T    = (u16*)(ws + 104 * MB);
    u16* Hb     = (u16*)(ws + 0 * MB);    // [8192][4096] bf16 = 64 MB
    u16* H2     = (u16*)(ws + 64 * MB);

    dim3 blk(256);
    cvt_f2b_kernel<<<dim3(8192), blk, 0, stream>>>(x, xb, 8192 * 1024);
    transpose_cvt<<<dim3(16, 16), blk, 0, stream>>>(Wq, WqkvT, 1024, 1024);
    transpose_cvt<<<dim3(16, 16), blk, 0, stream>>>(Wk, WqkvT + 1024 * 1024, 1024, 1024);
    transpose_cvt<<<dim3(16, 16), blk, 0, stream>>>(Wv, WqkvT + 2048 * 1024, 1024, 1024);
    transpose_cvt<<<dim3(64, 16), blk, 0, stream>>>(W1, W1T, 1024, 4096);

    gemm_qkv<<<dim3(24, 64), blk, 0, stream>>>(xb, WqkvT, bq, bk, bv,
                                               Qb, Kbf, Vt, 8192, 1024);

    transpose_cvt<<<dim3(16, 64), blk, 0, stream>>>(W2, W2T, 4096, 1024);

    attn_fwd<<<dim3(8, 128), blk, 0, stream>>>(Qb, Kbf, Vt, Ob);

    resln<0><<<dim3(8192), blk, 0, stream>>>(xb, Ob, X1);

    // FFN1: 256x256 8-phase (TM=8 ratios match m201), tanh-GELU epilogue
    gemm8p<1><<<dim3(16, 32), dim3(512), 0, stream>>>(X1, W1T, b1, Hb, 8192, 4096, 1024);
    // FFN2: reverted to m97 128x128 (round-8 measured-good config)
    gemm_bt<0><<<dim3(8, 64), blk, 0, stream>>>(Hb, W2T, b2, H2, 8192, 1024, 4096);

    resln<1><<<dim3(8192), blk, 0, stream>>>(X1, H2, out);
}

// Round 12
// 358.246 us; speedup vs baseline: 1.1262x; 1.0316x over previous
//
#include <hip/hip_runtime.h>

typedef unsigned short u16;
typedef __attribute__((ext_vector_type(8))) short bf16x8;   // 8 bf16 in 4 VGPRs
typedef __attribute__((ext_vector_type(4))) float f32x4;

#define MFMA16(a, b, c) __builtin_amdgcn_mfma_f32_16x16x32_bf16(a, b, c, 0, 0, 0)

__device__ __forceinline__ float b2f(u16 u) {
    unsigned int x = ((unsigned int)u) << 16;
    return __builtin_bit_cast(float, x);
}
__device__ __forceinline__ u16 f2b(float f) {
    unsigned int u = __builtin_bit_cast(unsigned int, f);
    u = u + 0x7fffu + ((u >> 16) & 1u);   // round-to-nearest-even
    return (u16)(u >> 16);
}
__device__ __forceinline__ u16 f2b_hi(float f) {   // truncation: 1 VALU op
    return (u16)(__builtin_bit_cast(unsigned int, f) >> 16);
}
// tanh-form GELU: max |err| vs exact erf-GELU ~3e-3; clamped arg -> no inf/NaN.
__device__ __forceinline__ float gelu_t(float x) {
    float xc = fminf(fmaxf(x, -8.f), 8.f);
    float tt = __builtin_amdgcn_exp2f(xc * (2.3022077f + 0.1029483f * xc * xc));
    return x * tt * __builtin_amdgcn_rcpf(1.f + tt);
}
__device__ __forceinline__ void gload_lds16(const u16* g, u16* lds) {
    __builtin_amdgcn_global_load_lds(
        (const __attribute__((address_space(1))) unsigned int*)g,
        (__attribute__((address_space(3))) unsigned int*)lds, 16, 0, 0);
}
__device__ __forceinline__ void barrier_raw() {
    asm volatile("" ::: "memory");
    __builtin_amdgcn_s_barrier();
    asm volatile("" ::: "memory");
}
// T1: bijective XCD-aware block remap (m204).
__device__ __forceinline__ void swz_block(int& mb, int& nb) {
    const int NX = gridDim.x;
    const int nwg = NX * gridDim.y;
    const int wg = blockIdx.y * NX + blockIdx.x;
    const int q = nwg >> 3, rmd = nwg & 7;
    const int xcd = wg & 7, idx = wg >> 3;
    const int swz = (xcd < rmd ? xcd * (q + 1) : rmd * (q + 1) + (xcd - rmd) * q) + idx;
    mb = swz / NX;
    nb = swz - mb * NX;
}

// ---------------------------------------------------------------------------
// fp32 -> bf16 cast
// ---------------------------------------------------------------------------
__global__ __launch_bounds__(256) void cvt_f2b_kernel(
    const float* __restrict__ in, u16* __restrict__ out, int n)
{
    const int i = (blockIdx.x * 256 + threadIdx.x) * 4;
    if (i >= n) return;
    float4 v = *(const float4*)&in[i];
    ushort4 o;
    o.x = f2b(v.x); o.y = f2b(v.y); o.z = f2b(v.z); o.w = f2b(v.w);
    *(ushort4*)&out[i] = o;
}

// ---------------------------------------------------------------------------
// fp32 [R][C] -> bf16 transposed [C][R]
// ---------------------------------------------------------------------------
__global__ __launch_bounds__(256) void transpose_cvt(
    const float* __restrict__ in, u16* __restrict__ out, int R, int C)
{
    __shared__ u16 tile[64][65];
    const int t = threadIdx.x;
    const int r0 = blockIdx.y * 64, c0 = blockIdx.x * 64;
    const int tr = t >> 4, tc = (t & 15) * 4;
#pragma unroll
    for (int p = 0; p < 4; p++) {
        const int rr = tr + p * 16;
        float4 v = *(const float4*)&in[(size_t)(r0 + rr) * C + c0 + tc];
        tile[rr][tc + 0] = f2b(v.x); tile[rr][tc + 1] = f2b(v.y);
        tile[rr][tc + 2] = f2b(v.z); tile[rr][tc + 3] = f2b(v.w);
    }
    __syncthreads();
#pragma unroll
    for (int p = 0; p < 4; p++) {
        const int cc = tr + p * 16;
        ushort4 v;
        v.x = tile[tc + 0][cc]; v.y = tile[tc + 1][cc];
        v.z = tile[tc + 2][cc]; v.w = tile[tc + 3][cc];
        *(ushort4*)&out[(size_t)(c0 + cc) * R + r0 + tc] = v;
    }
}

// ---------------------------------------------------------------------------
// m97-style GEMM: 128x128 tile, BK=32, 4 waves, 2-phase dbuf, T1 swizzle.
// ---------------------------------------------------------------------------
template <int EPI>
__global__ __launch_bounds__(256, 2) void gemm_bt(
    const u16* __restrict__ A, const u16* __restrict__ Bt,
    const float* __restrict__ bias, u16* __restrict__ C,
    int M, int N, int K)
{
    __shared__ __attribute__((aligned(16))) u16 sA[2][128 * 32];
    __shared__ __attribute__((aligned(16))) u16 sB[2][128 * 32];
    const int t = threadIdx.x;
    const int lane = t & 63, w = t >> 6;
    const int g = lane >> 4, r = lane & 15;
    const int wr = w >> 1, wc = w & 1;
    int mb, nb;
    swz_block(mb, nb);
    const int m0 = mb * 128, n0 = nb * 128;
    const int arow0 = t >> 2;
    const int ake = (t & 3) * 8;
    const int ldsb = w * 512;

    const f32x4 fz = {0.f, 0.f, 0.f, 0.f};
    f32x4 acc[4][4];
#pragma unroll
    for (int i = 0; i < 4; i++)
#pragma unroll
        for (int j = 0; j < 4; j++) acc[i][j] = fz;

#pragma unroll
    for (int it = 0; it < 2; ++it) {
        gload_lds16(&A[(size_t)(m0 + arow0 + it * 64) * K + ake], &sA[0][ldsb + it * 2048]);
        gload_lds16(&Bt[(size_t)(n0 + arow0 + it * 64) * K + ake], &sB[0][ldsb + it * 2048]);
    }
    __syncthreads();

    const int nk = K >> 5;
    for (int kt = 0; kt < nk; ++kt) {
        const int buf = kt & 1;
        if (kt + 1 < nk) {
            const int k0 = (kt + 1) << 5;
#pragma unroll
            for (int it = 0; it < 2; ++it) {
                gload_lds16(&A[(size_t)(m0 + arow0 + it * 64) * K + k0 + ake], &sA[buf ^ 1][ldsb + it * 2048]);
                gload_lds16(&Bt[(size_t)(n0 + arow0 + it * 64) * K + k0 + ake], &sB[buf ^ 1][ldsb + it * 2048]);
            }
        }
        bf16x8 af[4], bfr[4];
#pragma unroll
        for (int i = 0; i < 4; i++)
            af[i] = *(const bf16x8*)&sA[buf][(wr * 64 + i * 16 + r) * 32 + g * 8];
#pragma unroll
        for (int j = 0; j < 4; j++)
            bfr[j] = *(const bf16x8*)&sB[buf][(wc * 64 + j * 16 + r) * 32 + g * 8];
#pragma unroll
        for (int i = 0; i < 4; i++)
#pragma unroll
            for (int j = 0; j < 4; j++)
                acc[i][j] = MFMA16(af[i], bfr[j], acc[i][j]);
        __syncthreads();
    }

#pragma unroll
    for (int i = 0; i < 4; i++) {
#pragma unroll
        for (int j = 0; j < 4; j++) {
            const int col = n0 + wc * 64 + j * 16 + r;
            const float bs = bias[col];
            const int row0 = m0 + wr * 64 + i * 16 + g * 4;
#pragma unroll
            for (int rg = 0; rg < 4; ++rg) {
                float v = acc[i][j][rg] + bs;
                if (EPI == 1) v = gelu_t(v);
                C[(size_t)(row0 + rg) * N + col] = f2b(v);
            }
        }
    }
}

// ---------------------------------------------------------------------------
// Software-pipelined 8-phase GEMM, 256x256 tile, K compile-time (S=K/32 slices,
// fully unrolled). Per slice: vmcnt(counted) -> stage(s+3) -> barrier ->
// issue frag reads of slice s+1 -> setprio+32 MFMA(s) -> lgkmcnt(0) -> barrier.
// Frag-read latency hides under the MFMA block (the m196/m201 lever).
// Race audit: slot s+1 published by vmcnt(in-order, leave 4)+barrierA; stage of
// slot s-1 (iter s) ordered after its readers' lgkmcnt(0)+barrierB (iter s-2).
// ---------------------------------------------------------------------------
template <int K, int EPI>
__global__ __launch_bounds__(512, 2) void gemm8p(
    const u16* __restrict__ A, const u16* __restrict__ Bt,
    const float* __restrict__ bias, u16* __restrict__ C,
    int M, int N)
{
    constexpr int S = K >> 5;
    __shared__ __attribute__((aligned(16))) u16 As[4][256][32];
    __shared__ __attribute__((aligned(16))) u16 Bs[4][256][32];

    const int t = threadIdx.x;
    const int lane = t & 63;
    const int g = lane >> 4, r = lane & 15;
    const int wid = t >> 6, wm = wid >> 2, wn = wid & 3;
    int mb, nb;
    swz_block(mb, nb);
    const int m0 = mb * 256, n0 = nb * 256;

    const int srow = t >> 2;
    const int sslot = ((t & 3) ^ (srow & 3)) * 8;

    auto stageAB = [&](int u) {
        const int slot = u & 3, ks = u << 5;
#pragma unroll
        for (int h = 0; h < 2; ++h)
            gload_lds16(&A[(size_t)(m0 + srow + h * 128) * K + ks + sslot],
                        &As[slot][srow + h * 128][(t & 3) * 8]);
#pragma unroll
        for (int h = 0; h < 2; ++h)
            gload_lds16(&Bt[(size_t)(n0 + srow + h * 128) * K + ks + sslot],
                        &Bs[slot][srow + h * 128][(t & 3) * 8]);
    };

    f32x4 acc[8][4];
    const f32x4 fz = {0.f, 0.f, 0.f, 0.f};
#pragma unroll
    for (int i = 0; i < 8; ++i)
#pragma unroll
        for (int j = 0; j < 4; ++j) acc[i][j] = fz;

    stageAB(0); stageAB(1); stageAB(2);
    asm volatile("s_waitcnt vmcnt(8)" ::: "memory");   // slice 0 landed
    barrier_raw();

    const int swA = g ^ (r & 3);
    bf16x8 af[8], bf[4];
#pragma unroll
    for (int i = 0; i < 8; ++i)
        af[i] = *(const bf16x8*)&As[0][wm * 128 + i * 16 + r][swA * 8];
#pragma unroll
    for (int j = 0; j < 4; ++j)
        bf[j] = *(const bf16x8*)&Bs[0][wn * 64 + j * 16 + r][swA * 8];

#pragma unroll
    for (int s = 0; s < S; ++s) {
        bf16x8 afn[8], bfn[4];
        if (s < S - 1) {
            if (s < S - 2) asm volatile("s_waitcnt vmcnt(4)" ::: "memory");
            else           asm volatile("s_waitcnt vmcnt(0)" ::: "memory");
            if (s + 3 < S) stageAB(s + 3);
            barrier_raw();   // publish slice s+1 to all waves
            const int nslot = (s + 1) & 3;
#pragma unroll
            for (int i = 0; i < 8; ++i)
                afn[i] = *(const bf16x8*)&As[nslot][wm * 128 + i * 16 + r][swA * 8];
#pragma unroll
            for (int j = 0; j < 4; ++j)
                bfn[j] = *(const bf16x8*)&Bs[nslot][wn * 64 + j * 16 + r][swA * 8];
        }

        __builtin_amdgcn_s_setprio(1);
#pragma unroll
        for (int i = 0; i < 8; ++i) {
            acc[i][0] = MFMA16(af[i], bf[0], acc[i][0]);
            acc[i][1] = MFMA16(af[i], bf[1], acc[i][1]);
        }
#pragma unroll
        for (int i = 0; i < 8; ++i) {
            acc[i][2] = MFMA16(af[i], bf[2], acc[i][2]);
            acc[i][3] = MFMA16(af[i], bf[3], acc[i][3]);
        }
        __builtin_amdgcn_s_setprio(0);

        if (s < S - 1) {
            asm volatile("s_waitcnt lgkmcnt(0)" ::: "memory");   // frags(s+1) in regs
            __builtin_amdgcn_sched_barrier(0);                   // rule #18 fence
            barrier_raw();   // all waves done reading -> next stage may overwrite
#pragma unroll
            for (int i = 0; i < 8; ++i) af[i] = afn[i];
#pragma unroll
            for (int j = 0; j < 4; ++j) bf[j] = bfn[j];
        }
    }

#pragma unroll
    for (int i = 0; i < 8; ++i) {
        const int row0 = m0 + wm * 128 + i * 16 + g * 4;
#pragma unroll
        for (int j = 0; j < 4; ++j) {
            const int col = n0 + wn * 64 + j * 16 + r;
            const float bs = bias[col];
#pragma unroll
            for (int rg = 0; rg < 4; ++rg) {
                float v = acc[i][j][rg] + bs;
                if (EPI == 1) v = gelu_t(v);
                C[(size_t)(row0 + rg) * N + col] = f2b(v);
            }
        }
    }
}

// ---------------------------------------------------------------------------
// Fused QKV GEMM (m97 structure): N=3072 = [Q|K|V] vs WqkvT[3072][1024].
// ---------------------------------------------------------------------------
__global__ __launch_bounds__(256, 2) void gemm_qkv(
    const u16* __restrict__ A, const u16* __restrict__ Bt,
    const float* __restrict__ bq, const float* __restrict__ bk,
    const float* __restrict__ bv,
    u16* __restrict__ Qo, u16* __restrict__ Ko, u16* __restrict__ Vt,
    int M, int K)
{
    __shared__ __attribute__((aligned(16))) u16 sA[2][128 * 32];
    __shared__ __attribute__((aligned(16))) u16 sB[2][128 * 32];
    const int t = threadIdx.x;
    const int lane = t & 63, w = t >> 6;
    const int g = lane >> 4, r = lane & 15;
    const int wr = w >> 1, wc = w & 1;
    int mb, nb;
    swz_block(mb, nb);
    const int m0 = mb * 128, n0 = nb * 128;
    const int arow0 = t >> 2;
    const int ake = (t & 3) * 8;
    const int ldsb = w * 512;

    const f32x4 fz = {0.f, 0.f, 0.f, 0.f};
    f32x4 acc[4][4];
#pragma unroll
    for (int i = 0; i < 4; i++)
#pragma unroll
        for (int j = 0; j < 4; j++) acc[i][j] = fz;

#pragma unroll
    for (int it = 0; it < 2; ++it) {
        gload_lds16(&A[(size_t)(m0 + arow0 + it * 64) * K + ake], &sA[0][ldsb + it * 2048]);
        gload_lds16(&Bt[(size_t)(n0 + arow0 + it * 64) * K + ake], &sB[0][ldsb + it * 2048]);
    }
    __syncthreads();

    const int nk = K >> 5;
    for (int kt = 0; kt < nk; ++kt) {
        const int buf = kt & 1;
        if (kt + 1 < nk) {
            const int k0 = (kt + 1) << 5;
#pragma unroll
            for (int it = 0; it < 2; ++it) {
                gload_lds16(&A[(size_t)(m0 + arow0 + it * 64) * K + k0 + ake], &sA[buf ^ 1][ldsb + it * 2048]);
                gload_lds16(&Bt[(size_t)(n0 + arow0 + it * 64) * K + k0 + ake], &sB[buf ^ 1][ldsb + it * 2048]);
            }
        }
        bf16x8 af[4], bfr[4];
#pragma unroll
        for (int i = 0; i < 4; i++)
            af[i] = *(const bf16x8*)&sA[buf][(wr * 64 + i * 16 + r) * 32 + g * 8];
#pragma unroll
        for (int j = 0; j < 4; j++)
            bfr[j] = *(const bf16x8*)&sB[buf][(wc * 64 + j * 16 + r) * 32 + g * 8];
#pragma unroll
        for (int i = 0; i < 4; i++)
#pragma unroll
            for (int j = 0; j < 4; j++)
                acc[i][j] = MFMA16(af[i], bfr[j], acc[i][j]);
        __syncthreads();
    }

    const int sel = n0 >> 10;
    const float* bias = (sel == 0) ? bq : (sel == 1) ? bk : bv;
#pragma unroll
    for (int i = 0; i < 4; i++) {
#pragma unroll
        for (int j = 0; j < 4; j++) {
            const int col = n0 + wc * 64 + j * 16 + r;
            const int c1 = col & 1023;
            const float bs = bias[c1];
            const int row0 = m0 + wr * 64 + i * 16 + g * 4;
            if (sel < 2) {
                u16* C = sel ? Ko : Qo;
#pragma unroll
                for (int rg = 0; rg < 4; ++rg)
                    C[(size_t)(row0 + rg) * 1024 + c1] = f2b(acc[i][j][rg] + bs);
            } else {
                const int brow = row0 >> 10;
                const int l = row0 & 1023;
                const int vrow = ((brow << 4) + (c1 >> 6)) * 64 + (c1 & 63);
                ushort4 pk;
                pk.x = f2b(acc[i][j][0] + bs);
                pk.y = f2b(acc[i][j][1] + bs);
                pk.z = f2b(acc[i][j][2] + bs);
                pk.w = f2b(acc[i][j][3] + bs);
                *(ushort4*)&Vt[(size_t)vrow * 1024 + l] = pk;
            }
        }
    }
}

// ---------------------------------------------------------------------------
// Flash attention fwd (unchanged from round 10).
// ---------------------------------------------------------------------------
__global__ __launch_bounds__(256, 2) void attn_fwd(
    const u16* __restrict__ Q, const u16* __restrict__ Kb,
    const u16* __restrict__ Vt, u16* __restrict__ O)
{
    __shared__ __attribute__((aligned(16))) u16 sK[2][64 * 64];
    __shared__ __attribute__((aligned(16))) u16 sV[2][64 * 64];
    __shared__ __attribute__((aligned(16))) u16 sP[4][32 * 72];
    const int t = threadIdx.x;
    const int lane = t & 63, w = t >> 6;
    const int g = lane >> 4, r = lane & 15;
    const int bh = blockIdx.y;
    const int b = bh >> 4, h = bh & 15;
    const int q0 = blockIdx.x * 128;
    const size_t tokbase = (size_t)b << 10;
    const float SC = 0.125f * 1.44269504f;

    bf16x8 qf[2][2];
#pragma unroll
    for (int i = 0; i < 2; i++)
#pragma unroll
        for (int c = 0; c < 2; c++)
            qf[i][c] = *(const bf16x8*)&Q[((tokbase + q0 + w * 32 + i * 16 + r) << 10) + h * 64 + c * 32 + g * 8];

    const f32x4 fz = {0.f, 0.f, 0.f, 0.f};
    f32x4 acc[2][4];
    float lrow[2][4];
#pragma unroll
    for (int i = 0; i < 2; i++) {
#pragma unroll
        for (int j = 0; j < 4; j++) acc[i][j] = fz;
#pragma unroll
        for (int rg = 0; rg < 4; rg++) lrow[i][rg] = 0.f;
    }

    const int srow0 = t >> 3;
    const int skesw = ((t & 7) ^ ((t >> 3) & 7)) * 8;
    const int ldsb = w * 512;
    auto stageKV = [&](int kt, int bufsel) {
#pragma unroll
        for (int it = 0; it < 2; ++it) {
            const int row = srow0 + it * 32;
            gload_lds16(&Kb[((tokbase + kt * 64 + row) << 10) + h * 64 + skesw], &sK[bufsel][ldsb + it * 2048]);
            gload_lds16(&Vt[(((size_t)bh * 64 + row) << 10) + kt * 64 + skesw], &sV[bufsel][ldsb + it * 2048]);
        }
    };

    stageKV(0, 0);
    __syncthreads();

    for (int kt = 0; kt < 16; ++kt) {
        const int buf = kt & 1;
        if (kt < 15) stageKV(kt + 1, buf ^ 1);

        f32x4 s[2][4];
#pragma unroll
        for (int i = 0; i < 2; i++)
#pragma unroll
            for (int j = 0; j < 4; j++) s[i][j] = fz;
#pragma unroll
        for (int c = 0; c < 2; c++) {
            bf16x8 kf[4];
#pragma unroll
            for (int j = 0; j < 4; j++)
                kf[j] = *(const bf16x8*)&sK[buf][(j * 16 + r) * 64 + (((c * 4 + g) ^ (r & 7)) * 8)];
#pragma unroll
            for (int i = 0; i < 2; i++)
#pragma unroll
                for (int j = 0; j < 4; j++)
                    s[i][j] = MFMA16(qf[i][c], kf[j], s[i][j]);
        }

#pragma unroll
        for (int i = 0; i < 2; i++) {
#pragma unroll
            for (int rg = 0; rg < 4; rg++) {
                float p0 = __builtin_amdgcn_exp2f(s[i][0][rg] * SC);
                float p1 = __builtin_amdgcn_exp2f(s[i][1][rg] * SC);
                float p2 = __builtin_amdgcn_exp2f(s[i][2][rg] * SC);
                float p3 = __builtin_amdgcn_exp2f(s[i][3][rg] * SC);
                lrow[i][rg] += (p0 + p1) + (p2 + p3);
                const int prow = (i * 16 + g * 4 + rg) * 72;
                sP[w][prow + 0 * 16 + r] = f2b_hi(p0);
                sP[w][prow + 1 * 16 + r] = f2b_hi(p1);
                sP[w][prow + 2 * 16 + r] = f2b_hi(p2);
                sP[w][prow + 3 * 16 + r] = f2b_hi(p3);
            }
        }

#pragma unroll
        for (int c = 0; c < 2; c++) {
            bf16x8 pa[2], vb[4];
#pragma unroll
            for (int i = 0; i < 2; i++)
                pa[i] = *(const bf16x8*)&sP[w][(i * 16 + r) * 72 + c * 32 + g * 8];
#pragma unroll
            for (int j = 0; j < 4; j++)
                vb[j] = *(const bf16x8*)&sV[buf][(j * 16 + r) * 64 + (((c * 4 + g) ^ (r & 7)) * 8)];
#pragma unroll
            for (int i = 0; i < 2; i++)
#pragma unroll
                for (int j = 0; j < 4; j++)
                    acc[i][j] = MFMA16(pa[i], vb[j], acc[i][j]);
        }
        __syncthreads();
    }

#pragma unroll
    for (int i = 0; i < 2; i++)
#pragma unroll
        for (int rg = 0; rg < 4; rg++) {
            float l = lrow[i][rg];
            l += __shfl_xor(l, 1);
            l += __shfl_xor(l, 2);
            l += __shfl_xor(l, 4);
            l += __shfl_xor(l, 8);
            lrow[i][rg] = 1.0f / l;
        }
#pragma unroll
    for (int i = 0; i < 2; i++)
#pragma unroll
        for (int j = 0; j < 4; j++)
#pragma unroll
            for (int rg = 0; rg < 4; rg++) {
                const size_t row = tokbase + q0 + w * 32 + i * 16 + g * 4 + rg;
                const int col = h * 64 + j * 16 + r;
                O[(row << 10) + col] = f2b(acc[i][j][rg] * lrow[i][rg]);
            }
}

// ---------------------------------------------------------------------------
// out = LayerNorm(a + b)
// ---------------------------------------------------------------------------
template <int FP32OUT>
__global__ __launch_bounds__(256) void resln(
    const u16* __restrict__ a, const u16* __restrict__ bsrc, void* __restrict__ optr)
{
    const int row = blockIdx.x, t = threadIdx.x;
    const size_t base = (size_t)row << 10;
    ushort4 va = *(const ushort4*)&a[base + t * 4];
    ushort4 vb = *(const ushort4*)&bsrc[base + t * 4];
    float v0 = b2f(va.x) + b2f(vb.x);
    float v1 = b2f(va.y) + b2f(vb.y);
    float v2 = b2f(va.z) + b2f(vb.z);
    float v3 = b2f(va.w) + b2f(vb.w);
    float s = v0 + v1 + v2 + v3;
    float ss = v0 * v0 + v1 * v1 + v2 * v2 + v3 * v3;
#pragma unroll
    for (int m = 1; m < 64; m <<= 1) { s += __shfl_xor(s, m); ss += __shfl_xor(ss, m); }
    __shared__ float rs[4], rq[4];
    const int w = t >> 6;
    if ((t & 63) == 0) { rs[w] = s; rq[w] = ss; }
    __syncthreads();
    s = rs[0] + rs[1] + rs[2] + rs[3];
    ss = rq[0] + rq[1] + rq[2] + rq[3];
    const float mu = s * (1.0f / 1024.0f);
    const float var = ss * (1.0f / 1024.0f) - mu * mu;
    const float ri = rsqrtf(var + 1e-5f);
    if (FP32OUT) {
        float4 vo;
        vo.x = (v0 - mu) * ri; vo.y = (v1 - mu) * ri;
        vo.z = (v2 - mu) * ri; vo.w = (v3 - mu) * ri;
        *(float4*)&((float*)optr)[base + t * 4] = vo;
    } else {
        ushort4 vo;
        vo.x = f2b((v0 - mu) * ri); vo.y = f2b((v1 - mu) * ri);
        vo.z = f2b((v2 - mu) * ri); vo.w = f2b((v3 - mu) * ri);
        *(ushort4*)&((u16*)optr)[base + t * 4] = vo;
    }
}

// ---------------------------------------------------------------------------
extern "C" void kernel_launch(void* const* d_in, const int* in_sizes, int n_in,
                              void* d_out, int out_size, void* d_ws, size_t ws_size,
                              hipStream_t stream)
{
    (void)in_sizes; (void)n_in; (void)out_size; (void)ws_size;
    const float* x  = (const float*)d_in[0];
    const float* Wq = (const float*)d_in[1];
    const float* bq = (const float*)d_in[2];
    const float* Wk = (const float*)d_in[3];
    const float* bk = (const float*)d_in[4];
    const float* Wv = (const float*)d_in[5];
    const float* bv = (const float*)d_in[6];
    const float* W1 = (const float*)d_in[7];
    const float* b1 = (const float*)d_in[8];
    const float* W2 = (const float*)d_in[9];
    const float* b2 = (const float*)d_in[10];
    float* out = (float*)d_out;
    char* ws = (char*)d_ws;
    const size_t MB = 1u << 20;
    u16* Qb     = (u16*)(ws + 0 * MB);    // 16 MB } later reused as Hb (64 MB)
    u16* Kbf    = (u16*)(ws + 16 * MB);   // 16 MB }
    u16* Vt     = (u16*)(ws + 32 * MB);   // 16 MB }
    u16* Ob     = (u16*)(ws + 48 * MB);   // 16 MB }
    u16* xb     = (u16*)(ws + 64 * MB);   // 16 MB  later reused as H2
    u16* X1     = (u16*)(ws + 80 * MB);   // 16 MB
    u16* W1T    = (u16*)(ws + 96 * MB);   //  8 MB
    u16* WqkvT  = (u16*)(ws + 104 * MB);  //  6 MB } later reused as W2T (8 MB)
    u16* W2T    = (u16*)(ws + 104 * MB);
    u16* Hb     = (u16*)(ws + 0 * MB);    // [8192][4096] bf16 = 64 MB
    u16* H2     = (u16*)(ws + 64 * MB);

    dim3 blk(256);
    cvt_f2b_kernel<<<dim3(8192), blk, 0, stream>>>(x, xb, 8192 * 1024);
    transpose_cvt<<<dim3(16, 16), blk, 0, stream>>>(Wq, WqkvT, 1024, 1024);
    transpose_cvt<<<dim3(16, 16), blk, 0, stream>>>(Wk, WqkvT + 1024 * 1024, 1024, 1024);
    transpose_cvt<<<dim3(16, 16), blk, 0, stream>>>(Wv, WqkvT + 2048 * 1024, 1024, 1024);
    transpose_cvt<<<dim3(64, 16), blk, 0, stream>>>(W1, W1T, 1024, 4096);

    gemm_qkv<<<dim3(24, 64), blk, 0, stream>>>(xb, WqkvT, bq, bk, bv,
                                               Qb, Kbf, Vt, 8192, 1024);

    transpose_cvt<<<dim3(16, 64), blk, 0, stream>>>(W2, W2T, 4096, 1024);

    attn_fwd<<<dim3(8, 128), blk, 0, stream>>>(Qb, Kbf, Vt, Ob);

    resln<0><<<dim3(8192), blk, 0, stream>>>(xb, Ob, X1);

    // FFN1: 256x256 software-pipelined 8-phase (K=1024 compile-time), tanh-GELU
    gemm8p<1024, 1><<<dim3(16, 32), dim3(512), 0, stream>>>(X1, W1T, b1, Hb, 8192, 4096);
    // FFN2: m97 128x128 (round-8 measured-good config)
    gemm_bt<0><<<dim3(8, 64), blk, 0, stream>>>(Hb, W2T, b2, H2, 8192, 1024, 4096);

    resln<1><<<dim3(8192), blk, 0, stream>>>(X1, H2, out);
}

// Round 13
// 356.278 us; speedup vs baseline: 1.1324x; 1.0055x over previous
//
#include <hip/hip_runtime.h>

typedef unsigned short u16;
typedef __attribute__((ext_vector_type(8))) short bf16x8;   // 8 bf16 in 4 VGPRs
typedef __attribute__((ext_vector_type(4))) float f32x4;

#define MFMA16(a, b, c) __builtin_amdgcn_mfma_f32_16x16x32_bf16(a, b, c, 0, 0, 0)

__device__ __forceinline__ float b2f(u16 u) {
    unsigned int x = ((unsigned int)u) << 16;
    return __builtin_bit_cast(float, x);
}
__device__ __forceinline__ u16 f2b(float f) {
    unsigned int u = __builtin_bit_cast(unsigned int, f);
    u = u + 0x7fffu + ((u >> 16) & 1u);   // round-to-nearest-even
    return (u16)(u >> 16);
}
__device__ __forceinline__ u16 f2b_hi(float f) {   // truncation: 1 VALU op
    return (u16)(__builtin_bit_cast(unsigned int, f) >> 16);
}
// tanh-form GELU: max |err| vs exact erf-GELU ~3e-3; clamped arg -> no inf/NaN.
__device__ __forceinline__ float gelu_t(float x) {
    float xc = fminf(fmaxf(x, -8.f), 8.f);
    float tt = __builtin_amdgcn_exp2f(xc * (2.3022077f + 0.1029483f * xc * xc));
    return x * tt * __builtin_amdgcn_rcpf(1.f + tt);
}
__device__ __forceinline__ void gload_lds16(const u16* g, u16* lds) {
    __builtin_amdgcn_global_load_lds(
        (const __attribute__((address_space(1))) unsigned int*)g,
        (__attribute__((address_space(3))) unsigned int*)lds, 16, 0, 0);
}
__device__ __forceinline__ void barrier_raw() {
    asm volatile("" ::: "memory");
    __builtin_amdgcn_s_barrier();
    asm volatile("" ::: "memory");
}
// T1: bijective XCD-aware block remap (m204).
__device__ __forceinline__ void swz_block(int& mb, int& nb) {
    const int NX = gridDim.x;
    const int nwg = NX * gridDim.y;
    const int wg = blockIdx.y * NX + blockIdx.x;
    const int q = nwg >> 3, rmd = nwg & 7;
    const int xcd = wg & 7, idx = wg >> 3;
    const int swz = (xcd < rmd ? xcd * (q + 1) : rmd * (q + 1) + (xcd - rmd) * q) + idx;
    mb = swz / NX;
    nb = swz - mb * NX;
}

// ---------------------------------------------------------------------------
// fp32 -> bf16 cast
// ---------------------------------------------------------------------------
__global__ __launch_bounds__(256) void cvt_f2b_kernel(
    const float* __restrict__ in, u16* __restrict__ out, int n)
{
    const int i = (blockIdx.x * 256 + threadIdx.x) * 4;
    if (i >= n) return;
    float4 v = *(const float4*)&in[i];
    ushort4 o;
    o.x = f2b(v.x); o.y = f2b(v.y); o.z = f2b(v.z); o.w = f2b(v.w);
    *(ushort4*)&out[i] = o;
}

// ---------------------------------------------------------------------------
// fp32 [R][C] -> bf16 transposed [C][R]
// ---------------------------------------------------------------------------
__global__ __launch_bounds__(256) void transpose_cvt(
    const float* __restrict__ in, u16* __restrict__ out, int R, int C)
{
    __shared__ u16 tile[64][65];
    const int t = threadIdx.x;
    const int r0 = blockIdx.y * 64, c0 = blockIdx.x * 64;
    const int tr = t >> 4, tc = (t & 15) * 4;
#pragma unroll
    for (int p = 0; p < 4; p++) {
        const int rr = tr + p * 16;
        float4 v = *(const float4*)&in[(size_t)(r0 + rr) * C + c0 + tc];
        tile[rr][tc + 0] = f2b(v.x); tile[rr][tc + 1] = f2b(v.y);
        tile[rr][tc + 2] = f2b(v.z); tile[rr][tc + 3] = f2b(v.w);
    }
    __syncthreads();
#pragma unroll
    for (int p = 0; p < 4; p++) {
        const int cc = tr + p * 16;
        ushort4 v;
        v.x = tile[tc + 0][cc]; v.y = tile[tc + 1][cc];
        v.z = tile[tc + 2][cc]; v.w = tile[tc + 3][cc];
        *(ushort4*)&out[(size_t)(c0 + cc) * R + r0 + tc] = v;
    }
}

// ---------------------------------------------------------------------------
// m97-style GEMM: 128x128 tile, BK=32, 4 waves, 2-phase dbuf, T1 swizzle.
// ---------------------------------------------------------------------------
template <int EPI>
__global__ __launch_bounds__(256, 2) void gemm_bt(
    const u16* __restrict__ A, const u16* __restrict__ Bt,
    const float* __restrict__ bias, u16* __restrict__ C,
    int M, int N, int K)
{
    __shared__ __attribute__((aligned(16))) u16 sA[2][128 * 32];
    __shared__ __attribute__((aligned(16))) u16 sB[2][128 * 32];
    const int t = threadIdx.x;
    const int lane = t & 63, w = t >> 6;
    const int g = lane >> 4, r = lane & 15;
    const int wr = w >> 1, wc = w & 1;
    int mb, nb;
    swz_block(mb, nb);
    const int m0 = mb * 128, n0 = nb * 128;
    const int arow0 = t >> 2;
    const int ake = (t & 3) * 8;
    const int ldsb = w * 512;

    const f32x4 fz = {0.f, 0.f, 0.f, 0.f};
    f32x4 acc[4][4];
#pragma unroll
    for (int i = 0; i < 4; i++)
#pragma unroll
        for (int j = 0; j < 4; j++) acc[i][j] = fz;

#pragma unroll
    for (int it = 0; it < 2; ++it) {
        gload_lds16(&A[(size_t)(m0 + arow0 + it * 64) * K + ake], &sA[0][ldsb + it * 2048]);
        gload_lds16(&Bt[(size_t)(n0 + arow0 + it * 64) * K + ake], &sB[0][ldsb + it * 2048]);
    }
    __syncthreads();

    const int nk = K >> 5;
    for (int kt = 0; kt < nk; ++kt) {
        const int buf = kt & 1;
        if (kt + 1 < nk) {
            const int k0 = (kt + 1) << 5;
#pragma unroll
            for (int it = 0; it < 2; ++it) {
                gload_lds16(&A[(size_t)(m0 + arow0 + it * 64) * K + k0 + ake], &sA[buf ^ 1][ldsb + it * 2048]);
                gload_lds16(&Bt[(size_t)(n0 + arow0 + it * 64) * K + k0 + ake], &sB[buf ^ 1][ldsb + it * 2048]);
            }
        }
        bf16x8 af[4], bfr[4];
#pragma unroll
        for (int i = 0; i < 4; i++)
            af[i] = *(const bf16x8*)&sA[buf][(wr * 64 + i * 16 + r) * 32 + g * 8];
#pragma unroll
        for (int j = 0; j < 4; j++)
            bfr[j] = *(const bf16x8*)&sB[buf][(wc * 64 + j * 16 + r) * 32 + g * 8];
#pragma unroll
        for (int i = 0; i < 4; i++)
#pragma unroll
            for (int j = 0; j < 4; j++)
                acc[i][j] = MFMA16(af[i], bfr[j], acc[i][j]);
        __syncthreads();
    }

#pragma unroll
    for (int i = 0; i < 4; i++) {
#pragma unroll
        for (int j = 0; j < 4; j++) {
            const int col = n0 + wc * 64 + j * 16 + r;
            const float bs = bias[col];
            const int row0 = m0 + wr * 64 + i * 16 + g * 4;
#pragma unroll
            for (int rg = 0; rg < 4; ++rg) {
                float v = acc[i][j][rg] + bs;
                if (EPI == 1) v = gelu_t(v);
                C[(size_t)(row0 + rg) * N + col] = f2b(v);
            }
        }
    }
}

// ---------------------------------------------------------------------------
// Software-pipelined 8-phase GEMM, 256x256 tile, K compile-time (unchanged
// from round 11/12 — measured improvement, kept as-is).
// ---------------------------------------------------------------------------
template <int K, int EPI>
__global__ __launch_bounds__(512, 2) void gemm8p(
    const u16* __restrict__ A, const u16* __restrict__ Bt,
    const float* __restrict__ bias, u16* __restrict__ C,
    int M, int N)
{
    constexpr int S = K >> 5;
    __shared__ __attribute__((aligned(16))) u16 As[4][256][32];
    __shared__ __attribute__((aligned(16))) u16 Bs[4][256][32];

    const int t = threadIdx.x;
    const int lane = t & 63;
    const int g = lane >> 4, r = lane & 15;
    const int wid = t >> 6, wm = wid >> 2, wn = wid & 3;
    int mb, nb;
    swz_block(mb, nb);
    const int m0 = mb * 256, n0 = nb * 256;

    const int srow = t >> 2;
    const int sslot = ((t & 3) ^ (srow & 3)) * 8;

    auto stageAB = [&](int u) {
        const int slot = u & 3, ks = u << 5;
#pragma unroll
        for (int h = 0; h < 2; ++h)
            gload_lds16(&A[(size_t)(m0 + srow + h * 128) * K + ks + sslot],
                        &As[slot][srow + h * 128][(t & 3) * 8]);
#pragma unroll
        for (int h = 0; h < 2; ++h)
            gload_lds16(&Bt[(size_t)(n0 + srow + h * 128) * K + ks + sslot],
                        &Bs[slot][srow + h * 128][(t & 3) * 8]);
    };

    f32x4 acc[8][4];
    const f32x4 fz = {0.f, 0.f, 0.f, 0.f};
#pragma unroll
    for (int i = 0; i < 8; ++i)
#pragma unroll
        for (int j = 0; j < 4; ++j) acc[i][j] = fz;

    stageAB(0); stageAB(1); stageAB(2);
    asm volatile("s_waitcnt vmcnt(8)" ::: "memory");   // slice 0 landed
    barrier_raw();

    const int swA = g ^ (r & 3);
    bf16x8 af[8], bf[4];
#pragma unroll
    for (int i = 0; i < 8; ++i)
        af[i] = *(const bf16x8*)&As[0][wm * 128 + i * 16 + r][swA * 8];
#pragma unroll
    for (int j = 0; j < 4; ++j)
        bf[j] = *(const bf16x8*)&Bs[0][wn * 64 + j * 16 + r][swA * 8];

#pragma unroll
    for (int s = 0; s < S; ++s) {
        bf16x8 afn[8], bfn[4];
        if (s < S - 1) {
            if (s < S - 2) asm volatile("s_waitcnt vmcnt(4)" ::: "memory");
            else           asm volatile("s_waitcnt vmcnt(0)" ::: "memory");
            if (s + 3 < S) stageAB(s + 3);
            barrier_raw();   // publish slice s+1 to all waves
            const int nslot = (s + 1) & 3;
#pragma unroll
            for (int i = 0; i < 8; ++i)
                afn[i] = *(const bf16x8*)&As[nslot][wm * 128 + i * 16 + r][swA * 8];
#pragma unroll
            for (int j = 0; j < 4; ++j)
                bfn[j] = *(const bf16x8*)&Bs[nslot][wn * 64 + j * 16 + r][swA * 8];
        }

        __builtin_amdgcn_s_setprio(1);
#pragma unroll
        for (int i = 0; i < 8; ++i) {
            acc[i][0] = MFMA16(af[i], bf[0], acc[i][0]);
            acc[i][1] = MFMA16(af[i], bf[1], acc[i][1]);
        }
#pragma unroll
        for (int i = 0; i < 8; ++i) {
            acc[i][2] = MFMA16(af[i], bf[2], acc[i][2]);
            acc[i][3] = MFMA16(af[i], bf[3], acc[i][3]);
        }
        __builtin_amdgcn_s_setprio(0);

        if (s < S - 1) {
            asm volatile("s_waitcnt lgkmcnt(0)" ::: "memory");   // frags(s+1) in regs
            __builtin_amdgcn_sched_barrier(0);                   // rule #18 fence
            barrier_raw();   // all waves done reading -> next stage may overwrite
#pragma unroll
            for (int i = 0; i < 8; ++i) af[i] = afn[i];
#pragma unroll
            for (int j = 0; j < 4; ++j) bf[j] = bfn[j];
        }
    }

#pragma unroll
    for (int i = 0; i < 8; ++i) {
        const int row0 = m0 + wm * 128 + i * 16 + g * 4;
#pragma unroll
        for (int j = 0; j < 4; ++j) {
            const int col = n0 + wn * 64 + j * 16 + r;
            const float bs = bias[col];
#pragma unroll
            for (int rg = 0; rg < 4; ++rg) {
                float v = acc[i][j][rg] + bs;
                if (EPI == 1) v = gelu_t(v);
                C[(size_t)(row0 + rg) * N + col] = f2b(v);
            }
        }
    }
}

// ---------------------------------------------------------------------------
// Fused QKV GEMM (m97 structure): N=3072 = [Q|K|V] vs WqkvT[3072][1024].
// ---------------------------------------------------------------------------
__global__ __launch_bounds__(256, 2) void gemm_qkv(
    const u16* __restrict__ A, const u16* __restrict__ Bt,
    const float* __restrict__ bq, const float* __restrict__ bk,
    const float* __restrict__ bv,
    u16* __restrict__ Qo, u16* __restrict__ Ko, u16* __restrict__ Vt,
    int M, int K)
{
    __shared__ __attribute__((aligned(16))) u16 sA[2][128 * 32];
    __shared__ __attribute__((aligned(16))) u16 sB[2][128 * 32];
    const int t = threadIdx.x;
    const int lane = t & 63, w = t >> 6;
    const int g = lane >> 4, r = lane & 15;
    const int wr = w >> 1, wc = w & 1;
    int mb, nb;
    swz_block(mb, nb);
    const int m0 = mb * 128, n0 = nb * 128;
    const int arow0 = t >> 2;
    const int ake = (t & 3) * 8;
    const int ldsb = w * 512;

    const f32x4 fz = {0.f, 0.f, 0.f, 0.f};
    f32x4 acc[4][4];
#pragma unroll
    for (int i = 0; i < 4; i++)
#pragma unroll
        for (int j = 0; j < 4; j++) acc[i][j] = fz;

#pragma unroll
    for (int it = 0; it < 2; ++it) {
        gload_lds16(&A[(size_t)(m0 + arow0 + it * 64) * K + ake], &sA[0][ldsb + it * 2048]);
        gload_lds16(&Bt[(size_t)(n0 + arow0 + it * 64) * K + ake], &sB[0][ldsb + it * 2048]);
    }
    __syncthreads();

    const int nk = K >> 5;
    for (int kt = 0; kt < nk; ++kt) {
        const int buf = kt & 1;
        if (kt + 1 < nk) {
            const int k0 = (kt + 1) << 5;
#pragma unroll
            for (int it = 0; it < 2; ++it) {
                gload_lds16(&A[(size_t)(m0 + arow0 + it * 64) * K + k0 + ake], &sA[buf ^ 1][ldsb + it * 2048]);
                gload_lds16(&Bt[(size_t)(n0 + arow0 + it * 64) * K + k0 + ake], &sB[buf ^ 1][ldsb + it * 2048]);
            }
        }
        bf16x8 af[4], bfr[4];
#pragma unroll
        for (int i = 0; i < 4; i++)
            af[i] = *(const bf16x8*)&sA[buf][(wr * 64 + i * 16 + r) * 32 + g * 8];
#pragma unroll
        for (int j = 0; j < 4; j++)
            bfr[j] = *(const bf16x8*)&sB[buf][(wc * 64 + j * 16 + r) * 32 + g * 8];
#pragma unroll
        for (int i = 0; i < 4; i++)
#pragma unroll
            for (int j = 0; j < 4; j++)
                acc[i][j] = MFMA16(af[i], bfr[j], acc[i][j]);
        __syncthreads();
    }

    const int sel = n0 >> 10;
    const float* bias = (sel == 0) ? bq : (sel == 1) ? bk : bv;
#pragma unroll
    for (int i = 0; i < 4; i++) {
#pragma unroll
        for (int j = 0; j < 4; j++) {
            const int col = n0 + wc * 64 + j * 16 + r;
            const int c1 = col & 1023;
            const float bs = bias[c1];
            const int row0 = m0 + wr * 64 + i * 16 + g * 4;
            if (sel < 2) {
                u16* C = sel ? Ko : Qo;
#pragma unroll
                for (int rg = 0; rg < 4; ++rg)
                    C[(size_t)(row0 + rg) * 1024 + c1] = f2b(acc[i][j][rg] + bs);
            } else {
                const int brow = row0 >> 10;
                const int l = row0 & 1023;
                const int vrow = ((brow << 4) + (c1 >> 6)) * 64 + (c1 & 63);
                ushort4 pk;
                pk.x = f2b(acc[i][j][0] + bs);
                pk.y = f2b(acc[i][j][1] + bs);
                pk.z = f2b(acc[i][j][2] + bs);
                pk.w = f2b(acc[i][j][3] + bs);
                *(ushort4*)&Vt[(size_t)vrow * 1024 + l] = pk;
            }
        }
    }
}

// ---------------------------------------------------------------------------
// Flash attention fwd, SWAPPED QK^T (T12 core): s = mfma(K-frag, Q-frag) puts
// 4 CONSECUTIVE keys (g*4+rg) per register quad for q-col i*16+r. P-values
// pack via v_perm into one ds_write_b64 per (i,j): 32 ds_write_b16 -> 8
// ds_write_b64 per lane per tile. l-partials are lane-local (16 keys/lane);
// epilogue: 2-shuffle reduce + tiny wave-local sL table redistributes 1/l to
// acc's q-row layout. PV/staging/swizzle unchanged; math identical.
// ---------------------------------------------------------------------------
__global__ __launch_bounds__(256, 2) void attn_fwd(
    const u16* __restrict__ Q, const u16* __restrict__ Kb,
    const u16* __restrict__ Vt, u16* __restrict__ O)
{
    __shared__ __attribute__((aligned(16))) u16 sK[2][64 * 64];
    __shared__ __attribute__((aligned(16))) u16 sV[2][64 * 64];
    __shared__ __attribute__((aligned(16))) u16 sP[4][32 * 72];
    __shared__ float sL[4][32];
    const int t = threadIdx.x;
    const int lane = t & 63, w = t >> 6;
    const int g = lane >> 4, r = lane & 15;
    const int bh = blockIdx.y;
    const int b = bh >> 4, h = bh & 15;
    const int q0 = blockIdx.x * 128;
    const size_t tokbase = (size_t)b << 10;
    const float SC = 0.125f * 1.44269504f;

    bf16x8 qf[2][2];
#pragma unroll
    for (int i = 0; i < 2; i++)
#pragma unroll
        for (int c = 0; c < 2; c++)
            qf[i][c] = *(const bf16x8*)&Q[((tokbase + q0 + w * 32 + i * 16 + r) << 10) + h * 64 + c * 32 + g * 8];

    const f32x4 fz = {0.f, 0.f, 0.f, 0.f};
    f32x4 acc[2][4];
    float lrow[2] = {0.f, 0.f};   // per-LANE partial over this lane's 16 keys
#pragma unroll
    for (int i = 0; i < 2; i++)
#pragma unroll
        for (int j = 0; j < 4; j++) acc[i][j] = fz;

    const int srow0 = t >> 3;
    const int skesw = ((t & 7) ^ ((t >> 3) & 7)) * 8;
    const int ldsb = w * 512;
    auto stageKV = [&](int kt, int bufsel) {
#pragma unroll
        for (int it = 0; it < 2; ++it) {
            const int row = srow0 + it * 32;
            gload_lds16(&Kb[((tokbase + kt * 64 + row) << 10) + h * 64 + skesw], &sK[bufsel][ldsb + it * 2048]);
            gload_lds16(&Vt[(((size_t)bh * 64 + row) << 10) + kt * 64 + skesw], &sV[bufsel][ldsb + it * 2048]);
        }
    };

    stageKV(0, 0);
    __syncthreads();

    for (int kt = 0; kt < 16; ++kt) {
        const int buf = kt & 1;
        if (kt < 15) stageKV(kt + 1, buf ^ 1);

        // S^T = K Q^T : rows = keys (j*16 + g*4+rg), cols = q (i*16 + r)
        f32x4 s[2][4];
#pragma unroll
        for (int i = 0; i < 2; i++)
#pragma unroll
            for (int j = 0; j < 4; j++) s[i][j] = fz;
#pragma unroll
        for (int c = 0; c < 2; c++) {
            bf16x8 kf[4];
#pragma unroll
            for (int j = 0; j < 4; j++)
                kf[j] = *(const bf16x8*)&sK[buf][(j * 16 + r) * 64 + (((c * 4 + g) ^ (r & 7)) * 8)];
#pragma unroll
            for (int i = 0; i < 2; i++)
#pragma unroll
                for (int j = 0; j < 4; j++)
                    s[i][j] = MFMA16(kf[j], qf[i][c], s[i][j]);
        }

        // unnormalized P = exp2(S*SC); 4 consecutive keys -> 1 ds_write_b64
#pragma unroll
        for (int i = 0; i < 2; i++) {
#pragma unroll
            for (int j = 0; j < 4; j++) {
                float p0 = __builtin_amdgcn_exp2f(s[i][j][0] * SC);
                float p1 = __builtin_amdgcn_exp2f(s[i][j][1] * SC);
                float p2 = __builtin_amdgcn_exp2f(s[i][j][2] * SC);
                float p3 = __builtin_amdgcn_exp2f(s[i][j][3] * SC);
                lrow[i] += (p0 + p1) + (p2 + p3);
                unsigned int u0 = __builtin_bit_cast(unsigned int, p0);
                unsigned int u1 = __builtin_bit_cast(unsigned int, p1);
                unsigned int u2 = __builtin_bit_cast(unsigned int, p2);
                unsigned int u3 = __builtin_bit_cast(unsigned int, p3);
                uint2 pk;
                pk.x = __builtin_amdgcn_perm(u1, u0, 0x07060302u);  // [hi16(p0)|hi16(p1)]
                pk.y = __builtin_amdgcn_perm(u3, u2, 0x07060302u);
                *(uint2*)&sP[w][(i * 16 + r) * 72 + j * 16 + g * 4] = pk;
            }
        }

        // O += P V  (pa rows = q, unchanged)
#pragma unroll
        for (int c = 0; c < 2; c++) {
            bf16x8 pa[2], vb[4];
#pragma unroll
            for (int i = 0; i < 2; i++)
                pa[i] = *(const bf16x8*)&sP[w][(i * 16 + r) * 72 + c * 32 + g * 8];
#pragma unroll
            for (int j = 0; j < 4; j++)
                vb[j] = *(const bf16x8*)&sV[buf][(j * 16 + r) * 64 + (((c * 4 + g) ^ (r & 7)) * 8)];
#pragma unroll
            for (int i = 0; i < 2; i++)
#pragma unroll
                for (int j = 0; j < 4; j++)
                    acc[i][j] = MFMA16(pa[i], vb[j], acc[i][j]);
        }
        __syncthreads();
    }

    // reduce l across the 4 g-lanes sharing (q = i*16+r); park 1/l in sL
#pragma unroll
    for (int i = 0; i < 2; i++) {
        float l = lrow[i];
        l += __shfl_xor(l, 16);
        l += __shfl_xor(l, 32);
        if (g == 0) sL[w][i * 16 + r] = 1.0f / l;
    }
    asm volatile("s_waitcnt lgkmcnt(0)" ::: "memory");
    __builtin_amdgcn_sched_barrier(0);   // rule #18 fence

#pragma unroll
    for (int i = 0; i < 2; i++) {
        const float4 linv = *(const float4*)&sL[w][i * 16 + g * 4];
#pragma unroll
        for (int j = 0; j < 4; j++)
#pragma unroll
            for (int rg = 0; rg < 4; rg++) {
                const size_t row = tokbase + q0 + w * 32 + i * 16 + g * 4 + rg;
                const int col = h * 64 + j * 16 + r;
                O[(row << 10) + col] = f2b(acc[i][j][rg] * (&linv.x)[rg]);
            }
    }
}

// ---------------------------------------------------------------------------
// out = LayerNorm(a + b)
// ---------------------------------------------------------------------------
template <int FP32OUT>
__global__ __launch_bounds__(256) void resln(
    const u16* __restrict__ a, const u16* __restrict__ bsrc, void* __restrict__ optr)
{
    const int row = blockIdx.x, t = threadIdx.x;
    const size_t base = (size_t)row << 10;
    ushort4 va = *(const ushort4*)&a[base + t * 4];
    ushort4 vb = *(const ushort4*)&bsrc[base + t * 4];
    float v0 = b2f(va.x) + b2f(vb.x);
    float v1 = b2f(va.y) + b2f(vb.y);
    float v2 = b2f(va.z) + b2f(vb.z);
    float v3 = b2f(va.w) + b2f(vb.w);
    float s = v0 + v1 + v2 + v3;
    float ss = v0 * v0 + v1 * v1 + v2 * v2 + v3 * v3;
#pragma unroll
    for (int m = 1; m < 64; m <<= 1) { s += __shfl_xor(s, m); ss += __shfl_xor(ss, m); }
    __shared__ float rs[4], rq[4];
    const int w = t >> 6;
    if ((t & 63) == 0) { rs[w] = s; rq[w] = ss; }
    __syncthreads();
    s = rs[0] + rs[1] + rs[2] + rs[3];
    ss = rq[0] + rq[1] + rq[2] + rq[3];
    const float mu = s * (1.0f / 1024.0f);
    const float var = ss * (1.0f / 1024.0f) - mu * mu;
    const float ri = rsqrtf(var + 1e-5f);
    if (FP32OUT) {
        float4 vo;
        vo.x = (v0 - mu) * ri; vo.y = (v1 - mu) * ri;
        vo.z = (v2 - mu) * ri; vo.w = (v3 - mu) * ri;
        *(float4*)&((float*)optr)[base + t * 4] = vo;
    } else {
        ushort4 vo;
        vo.x = f2b((v0 - mu) * ri); vo.y = f2b((v1 - mu) * ri);
        vo.z = f2b((v2 - mu) * ri); vo.w = f2b((v3 - mu) * ri);
        *(ushort4*)&((u16*)optr)[base + t * 4] = vo;
    }
}

// ---------------------------------------------------------------------------
extern "C" void kernel_launch(void* const* d_in, const int* in_sizes, int n_in,
                              void* d_out, int out_size, void* d_ws, size_t ws_size,
                              hipStream_t stream)
{
    (void)in_sizes; (void)n_in; (void)out_size; (void)ws_size;
    const float* x  = (const float*)d_in[0];
    const float* Wq = (const float*)d_in[1];
    const float* bq = (const float*)d_in[2];
    const float* Wk = (const float*)d_in[3];
    const float* bk = (const float*)d_in[4];
    const float* Wv = (const float*)d_in[5];
    const float* bv = (const float*)d_in[6];
    const float* W1 = (const float*)d_in[7];
    const float* b1 = (const float*)d_in[8];
    const float* W2 = (const float*)d_in[9];
    const float* b2 = (const float*)d_in[10];
    float* out = (float*)d_out;
    char* ws = (char*)d_ws;
    const size_t MB = 1u << 20;
    u16* Qb     = (u16*)(ws + 0 * MB);    // 16 MB } later reused as Hb (64 MB)
    u16* Kbf    = (u16*)(ws + 16 * MB);   // 16 MB }
    u16* Vt     = (u16*)(ws + 32 * MB);   // 16 MB }
    u16* Ob     = (u16*)(ws + 48 * MB);   // 16 MB }
    u16* xb     = (u16*)(ws + 64 * MB);   // 16 MB  later reused as H2
    u16* X1     = (u16*)(ws + 80 * MB);   // 16 MB
    u16* W1T    = (u16*)(ws + 96 * MB);   //  8 MB
    u16* WqkvT  = (u16*)(ws + 104 * MB);  //  6 MB } later reused as W2T (8 MB)
    u16* W2T    = (u16*)(ws + 104 * MB);
    u16* Hb     = (u16*)(ws + 0 * MB);    // [8192][4096] bf16 = 64 MB
    u16* H2     = (u16*)(ws + 64 * MB);

    dim3 blk(256);
    cvt_f2b_kernel<<<dim3(8192), blk, 0, stream>>>(x, xb, 8192 * 1024);
    transpose_cvt<<<dim3(16, 16), blk, 0, stream>>>(Wq, WqkvT, 1024, 1024);
    transpose_cvt<<<dim3(16, 16), blk, 0, stream>>>(Wk, WqkvT + 1024 * 1024, 1024, 1024);
    transpose_cvt<<<dim3(16, 16), blk, 0, stream>>>(Wv, WqkvT + 2048 * 1024, 1024, 1024);
    transpose_cvt<<<dim3(64, 16), blk, 0, stream>>>(W1, W1T, 1024, 4096);

    gemm_qkv<<<dim3(24, 64), blk, 0, stream>>>(xb, WqkvT, bq, bk, bv,
                                               Qb, Kbf, Vt, 8192, 1024);

    transpose_cvt<<<dim3(16, 64), blk, 0, stream>>>(W2, W2T, 4096, 1024);

    attn_fwd<<<dim3(8, 128), blk, 0, stream>>>(Qb, Kbf, Vt, Ob);

    resln<0><<<dim3(8192), blk, 0, stream>>>(xb, Ob, X1);

    // FFN1: 256x256 software-pipelined 8-phase (K=1024 compile-time), tanh-GELU
    gemm8p<1024, 1><<<dim3(16, 32), dim3(512), 0, stream>>>(X1, W1T, b1, Hb, 8192, 4096);
    // FFN2: m97 128x128 (round-8 measured-good config)
    gemm_bt<0><<<dim3(8, 64), blk, 0, stream>>>(Hb, W2T, b2, H2, 8192, 1024, 4096);

    resln<1><<<dim3(8192), blk, 0, stream>>>(X1, H2, out);
}